// Round 5
// baseline (476.481 us; speedup 1.0000x reference)
//
#include <hip/hip_runtime.h>
#include <math.h>

#define TPB 256

typedef unsigned short ushort_t;
typedef __attribute__((ext_vector_type(8))) short short8v;     // 8 bf16 (4 VGPRs), MFMA A/B frag
typedef __attribute__((ext_vector_type(4))) float f32x4;       // MFMA C/D frag
typedef __attribute__((ext_vector_type(8))) unsigned short ushort8;

__device__ __forceinline__ float b2f(unsigned short u) {
  union { unsigned int i; float f; } c; c.i = ((unsigned int)u) << 16; return c.f;
}
__device__ __forceinline__ unsigned short f2b(float f) {
  union { float f; unsigned int i; } c; c.f = f;
  unsigned int x = c.i;
  x += 0x7FFFu + ((x >> 16) & 1u);           // round-to-nearest-even
  return (unsigned short)(x >> 16);
}

// ---------------- CSR build (padded to multiple of 8 per node) ----------------
__global__ void k_hist(const int* __restrict__ dst, int* deg, int E) {
  int e = blockIdx.x * TPB + threadIdx.x;
  if (e < E) atomicAdd(&deg[dst[e]], 1);
}

__global__ void k_gcnt(const int* __restrict__ batch, int* gcnt, int N) {
  int t = blockIdx.x * TPB + threadIdx.x;
  int n0 = t * 16;
  if (n0 >= N) return;
  int n1 = min(n0 + 16, N);
  int cur = batch[n0];
  int c = 0;
  for (int n = n0; n < n1; ++n) {
    int b = batch[n];
    if (b != cur) { atomicAdd(&gcnt[cur], c); cur = b; c = 0; }
    ++c;
  }
  atomicAdd(&gcnt[cur], c);
}

// scan input = deg rounded up to multiple of 8
__global__ void k_scan1(const int* __restrict__ deg, int* rp, int* bsum, int N) {
  __shared__ int s[TPB];
  int t = threadIdx.x;
  int i = blockIdx.x * TPB + t;
  int v = (i < N) ? ((deg[i] + 7) & ~7) : 0;
  s[t] = v;
  __syncthreads();
  for (int d = 1; d < TPB; d <<= 1) {
    int u = (t >= d) ? s[t - d] : 0;
    __syncthreads();
    s[t] += u;
    __syncthreads();
  }
  if (i < N) rp[i] = s[t] - v;
  if (t == TPB - 1) bsum[blockIdx.x] = s[t];
}

__global__ void k_scan2(const int* bsum, int* boff, int nb) {
  __shared__ int s[1024];
  int t = threadIdx.x;
  int v = (t < nb) ? bsum[t] : 0;
  s[t] = v;
  __syncthreads();
  for (int d = 1; d < 1024; d <<= 1) {
    int u = (t >= d) ? s[t - d] : 0;
    __syncthreads();
    s[t] += u;
    __syncthreads();
  }
  if (t < nb) boff[t] = s[t] - v;
}

__global__ void k_scan3(int* rp, const int* __restrict__ boff, const int* __restrict__ bsum,
                        int* cursor, int N, int nb) {
  int i = blockIdx.x * TPB + threadIdx.x;
  if (i < N) {
    int v = rp[i] + boff[i >> 8];
    rp[i] = v;
    cursor[i] = v;
  } else if (i == N) {
    rp[N] = boff[nb - 1] + bsum[nb - 1];       // total padded edges
  }
}

__global__ void k_fill(const int* __restrict__ src, const int* __restrict__ dst,
                       int* cursor, int* __restrict__ csr, int E) {
  int e = blockIdx.x * TPB + threadIdx.x;
  if (e < E) {
    int p = atomicAdd(&cursor[dst[e]], 1);
    csr[p] = src[e];
  }
}

// fill dummy slots with index N (dedicated zero row)
__global__ void k_pad(const int* __restrict__ cursor, const int* __restrict__ rp,
                      int* __restrict__ csr, int N) {
  int n = blockIdx.x * TPB + threadIdx.x;
  if (n >= N) return;
  int c = cursor[n], e = rp[n + 1];
  for (int p = c; p < e; ++p) csr[p] = N;
}

// ---------------- weight fp32 -> bf16 ----------------
__global__ void k_cvtw(const float* __restrict__ s0, const float* __restrict__ s1,
                       const float* __restrict__ s2, const float* __restrict__ s3,
                       ushort_t* d0, ushort_t* d1, ushort_t* d2, ushort_t* d3, int n) {
  int i = blockIdx.x * TPB + threadIdx.x;
  if (i < n) { d0[i] = f2b(s0[i]); d1[i] = f2b(s1[i]); d2[i] = f2b(s2[i]); d3[i] = f2b(s3[i]); }
}

// ---------------- Layer 1 (F=1), real-edge prefix only ----------------
__global__ void k_agg1(const float4* __restrict__ x, const int* __restrict__ rp,
                       const int* __restrict__ deg, const int* __restrict__ csr,
                       float4* __restrict__ agg1, int N) {
  int n = blockIdx.x * TPB + threadIdx.x;
  if (n >= N) return;
  int b = rp[n], d = deg[n], e = b + d;
  float4 a = make_float4(0.f, 0.f, 0.f, 0.f);
  int i = b;
  for (; i + 1 < e; i += 2) {
    float4 v0 = x[csr[i]];
    float4 v1 = x[csr[i + 1]];
    a.x += v0.x + v1.x; a.y += v0.y + v1.y;
    a.z += v0.z + v1.z; a.w += v0.w + v1.w;
  }
  if (i < e) {
    float4 v = x[csr[i]];
    a.x += v.x; a.y += v.y; a.z += v.z; a.w += v.w;
  }
  float inv = (d > 0) ? 1.f / (float)d : 0.f;
  a.x *= inv; a.y *= inv; a.z *= inv; a.w *= inv;
  agg1[n] = a;
}

// h1 flat[(n*4+m)*64 + c] = relu(agg1[n*4+m]*W1l[c] + b1l[c] + x[n*4+m]*W1r[c]), bf16 out
__global__ void k_l1(const float* __restrict__ x, const float* __restrict__ agg1,
                     const float* __restrict__ W1l, const float* __restrict__ b1l,
                     const float* __restrict__ W1r, ushort_t* __restrict__ h, int rows) {
  int q = blockIdx.x * TPB + threadIdx.x;
  if (q >= rows * 8) return;
  int r = q >> 3, c8 = (q & 7) * 8;
  float a = agg1[r], xx = x[r];
  ushort8 o;
#pragma unroll
  for (int k = 0; k < 8; ++k) {
    float v = fmaxf(a * W1l[c8 + k] + b1l[c8 + k] + xx * W1r[c8 + k], 0.f);
    o[k] = f2b(v);
  }
  *(ushort8*)(h + (size_t)r * 64 + c8) = o;
}

// ---------------- Fused layer: mean-agg gather + dual MFMA GEMM + bias + relu ----------
// Block: 256 threads = 4 waves = 32 nodes = 128 GEMM rows.
// Gather: 8 groups of 32 lanes; group owns 4 nodes sequentially; lane owns 8 features
// (one 16B load/neighbor); neighbor loop exactly deg_pad/8 iterations (CSR padded),
// 8 loads in flight per lane. Dummy edges read zeroed row N (L1-resident).
__global__ __launch_bounds__(256) void k_layer(
    const ushort_t* __restrict__ hIn, const int* __restrict__ rp,
    const int* __restrict__ deg, const int* __restrict__ csr,
    const ushort_t* __restrict__ Wlb, const ushort_t* __restrict__ Wrb,
    const float* __restrict__ bias, ushort_t* __restrict__ hOut, int N) {
  __shared__ ushort_t As[8192];                 // [128 rows][64 bf16], 16B-unit XOR swizzle
  int t = threadIdx.x;
  int wave = t >> 6, lane = t & 63;
  int g = lane >> 4, l15 = lane & 15;
  int q = t >> 5, l31 = t & 31;                 // gather group / lane-in-group
  int n0 = blockIdx.x * 32;
  int r0 = blockIdx.x * 128;
  int rows = N * 4;

  const ushort_t* hsl = hIn + l31 * 8;          // lane's 8-feature slice

#pragma unroll
  for (int k = 0; k < 4; ++k) {
    int nl = q * 4 + k;
    int n = n0 + nl;
    float acc[8];
#pragma unroll
    for (int j = 0; j < 8; ++j) acc[j] = 0.f;
    float inv = 0.f;
    if (n < N) {
      int b = rp[n], e = rp[n + 1];
      for (int i = b; i < e; i += 8) {
        int4 c0 = *(const int4*)(csr + i);
        int4 c1 = *(const int4*)(csr + i + 4);
        ushort8 v0 = *(const ushort8*)(hsl + (size_t)c0.x * 256);
        ushort8 v1 = *(const ushort8*)(hsl + (size_t)c0.y * 256);
        ushort8 v2 = *(const ushort8*)(hsl + (size_t)c0.z * 256);
        ushort8 v3 = *(const ushort8*)(hsl + (size_t)c0.w * 256);
        ushort8 v4 = *(const ushort8*)(hsl + (size_t)c1.x * 256);
        ushort8 v5 = *(const ushort8*)(hsl + (size_t)c1.y * 256);
        ushort8 v6 = *(const ushort8*)(hsl + (size_t)c1.z * 256);
        ushort8 v7 = *(const ushort8*)(hsl + (size_t)c1.w * 256);
#pragma unroll
        for (int j = 0; j < 8; ++j)
          acc[j] += ((b2f(v0[j]) + b2f(v1[j])) + (b2f(v2[j]) + b2f(v3[j])))
                  + ((b2f(v4[j]) + b2f(v5[j])) + (b2f(v6[j]) + b2f(v7[j])));
      }
      int d = deg[n];
      inv = (d > 0) ? 1.f / (float)d : 0.f;
    }
    ushort8 pk;
#pragma unroll
    for (int j = 0; j < 8; ++j) pk[j] = f2b(acc[j] * inv);
    int row = nl * 4 + (l31 >> 3);
    int cb = (l31 & 7) * 16;
    *(ushort8*)((char*)As + row * 128 + (cb ^ ((row & 7) << 4))) = pk;
  }
  __syncthreads();

  // ---- GEMM: wave owns rows [wave*32, wave*32+32) = 2 tiles of 16 ----
  short8v af[2][2], hf[2][2];
#pragma unroll
  for (int tile = 0; tile < 2; ++tile) {
    int arow = wave * 32 + tile * 16 + l15;
    int xr = (arow & 7) << 4;
    af[tile][0] = *(const short8v*)((char*)As + arow * 128 + ((g * 16) ^ xr));
    af[tile][1] = *(const short8v*)((char*)As + arow * 128 + ((g * 16 + 64) ^ xr));
    int rbase = r0 + arow;
    if (rbase > rows - 1) rbase = rows - 1;
    const ushort_t* hrow = hIn + (size_t)rbase * 64;
    hf[tile][0] = *(const short8v*)(hrow + g * 8);
    hf[tile][1] = *(const short8v*)(hrow + 32 + g * 8);
  }

  f32x4 fac[4][2];
#pragma unroll
  for (int c = 0; c < 4; ++c) {
    float bv = bias[c * 16 + l15];
    const ushort_t* wl = Wlb + (size_t)(c * 16 + l15) * 64;
    const ushort_t* wr = Wrb + (size_t)(c * 16 + l15) * 64;
    short8v bl0 = *(const short8v*)(wl + g * 8);
    short8v bl1 = *(const short8v*)(wl + 32 + g * 8);
    short8v br0 = *(const short8v*)(wr + g * 8);
    short8v br1 = *(const short8v*)(wr + 32 + g * 8);
#pragma unroll
    for (int tile = 0; tile < 2; ++tile) {
      fac[c][tile] = (f32x4){bv, bv, bv, bv};
      fac[c][tile] = __builtin_amdgcn_mfma_f32_16x16x32_bf16(af[tile][0], bl0, fac[c][tile], 0, 0, 0);
      fac[c][tile] = __builtin_amdgcn_mfma_f32_16x16x32_bf16(af[tile][1], bl1, fac[c][tile], 0, 0, 0);
      fac[c][tile] = __builtin_amdgcn_mfma_f32_16x16x32_bf16(hf[tile][0], br0, fac[c][tile], 0, 0, 0);
      fac[c][tile] = __builtin_amdgcn_mfma_f32_16x16x32_bf16(hf[tile][1], br1, fac[c][tile], 0, 0, 0);
    }
  }

  // ---- C/D: col = lane&15, row = (lane>>4)*4 + reg ----
#pragma unroll
  for (int tile = 0; tile < 2; ++tile) {
#pragma unroll
    for (int c = 0; c < 4; ++c) {
#pragma unroll
      for (int i2 = 0; i2 < 4; ++i2) {
        int grow = r0 + wave * 32 + tile * 16 + g * 4 + i2;
        if (grow < rows)
          hOut[(size_t)grow * 64 + c * 16 + l15] = f2b(fmaxf(fac[c][tile][i2], 0.f));
      }
    }
  }
}

// ---------------- Pooling (batch sorted: run-length accumulate), bf16 in ----------------
__global__ void k_pool(const ushort_t* __restrict__ h, const int* __restrict__ batch,
                       float* pooled, int N) {
  int t = threadIdx.x;
  int nPer = (N + gridDim.x - 1) / gridDim.x;
  int n0 = blockIdx.x * nPer;
  int n1 = min(N, n0 + nPer);
  if (n0 >= n1) return;
  float acc = 0.f;
  int cur = batch[n0];
  for (int n = n0; n < n1; ++n) {
    int b = batch[n];
    if (b != cur) {
      atomicAdd(&pooled[cur * 256 + t], acc);
      acc = 0.f;
      cur = b;
    }
    acc += b2f(h[(size_t)n * 256 + t]);
  }
  atomicAdd(&pooled[cur * 256 + t], acc);
}

__global__ void k_final(const float* __restrict__ pooled, const int* __restrict__ gcnt,
                        const float* __restrict__ Wlin, const float* __restrict__ blin,
                        float* __restrict__ out, int B) {
  int t = blockIdx.x * TPB + threadIdx.x;
  int b = t >> 2, j = t & 3;
  if (b >= B) return;
  float inv = 1.f / fmaxf((float)gcnt[b], 1.f);
  float s = blin[0];
  const float* p = pooled + b * 256 + j * 64;
#pragma unroll
  for (int f = 0; f < 64; ++f) s += p[f] * inv * Wlin[f];
  float z = 1.f / (1.f + expf(-s));
  z += __shfl_xor(z, 1);
  z += __shfl_xor(z, 2);
  if (j == 0) out[b] = 0.25f * z;
}

// ---------------- Host launcher ----------------
extern "C" void kernel_launch(void* const* d_in, const int* in_sizes, int n_in,
                              void* d_out, int out_size, void* d_ws, size_t ws_size,
                              hipStream_t stream) {
  const float* x   = (const float*)d_in[0];
  const int* edge  = (const int*)d_in[1];
  const int* batch = (const int*)d_in[2];
  const float* W1l = (const float*)d_in[3];
  const float* b1l = (const float*)d_in[4];
  const float* W1r = (const float*)d_in[5];
  const float* W2l = (const float*)d_in[6];
  const float* b2l = (const float*)d_in[7];
  const float* W2r = (const float*)d_in[8];
  const float* W3l = (const float*)d_in[9];
  const float* b3l = (const float*)d_in[10];
  const float* W3r = (const float*)d_in[11];
  const float* Wlin = (const float*)d_in[12];
  const float* blin = (const float*)d_in[13];
  float* out = (float*)d_out;

  const int N = in_sizes[0] / 4;          // x: [N,1,4]
  const int E = in_sizes[1] / 2;          // edge_index: [2,E]
  const int B = out_size;
  const int rows = 4 * N;

  const int* srcA = edge;
  const int* dstA = edge + E;

  // workspace carve (~112 MB total)
  char* p = (char*)d_ws;
  auto carve = [&](size_t bytes) -> void* {
    void* r = (void*)p;
    p += (bytes + 255) & ~(size_t)255;
    return r;
  };
  int* deg     = (int*)carve((size_t)N * 4);
  int* rp      = (int*)carve((size_t)(N + 1) * 4);   // padded row pointers
  int* cursor  = (int*)carve((size_t)N * 4);
  int* bsum    = (int*)carve(4096);
  int* boff    = (int*)carve(4096);
  int* gcnt    = (int*)carve((size_t)B * 4);
  int* csr     = (int*)carve(((size_t)E + 8 * (size_t)N) * 4);
  float* agg1  = (float*)carve((size_t)N * 4 * 4);
  float* pooled = (float*)carve((size_t)B * 256 * 4);
  ushort_t* Wb2l = (ushort_t*)carve(4096 * 2);
  ushort_t* Wb2r = (ushort_t*)carve(4096 * 2);
  ushort_t* Wb3l = (ushort_t*)carve(4096 * 2);
  ushort_t* Wb3r = (ushort_t*)carve(4096 * 2);
  ushort_t* hA = (ushort_t*)carve(((size_t)N + 1) * 256 * 2);  // +1 zero row
  ushort_t* hB = (ushort_t*)carve(((size_t)N + 1) * 256 * 2);
  (void)ws_size; (void)n_in;

  hipMemsetAsync(deg, 0, (size_t)N * 4, stream);
  hipMemsetAsync(gcnt, 0, (size_t)B * 4, stream);
  hipMemsetAsync(pooled, 0, (size_t)B * 256 * 4, stream);
  hipMemsetAsync(hA + (size_t)N * 256, 0, 512, stream);        // zero row
  hipMemsetAsync(hB + (size_t)N * 256, 0, 512, stream);

  int nbScan = (N + TPB - 1) / TPB;

  k_hist<<<(E + TPB - 1) / TPB, TPB, 0, stream>>>(dstA, deg, E);
  k_gcnt<<<((N + 15) / 16 + TPB - 1) / TPB, TPB, 0, stream>>>(batch, gcnt, N);
  k_cvtw<<<16, TPB, 0, stream>>>(W2l, W2r, W3l, W3r, Wb2l, Wb2r, Wb3l, Wb3r, 4096);
  k_scan1<<<nbScan, TPB, 0, stream>>>(deg, rp, bsum, N);
  k_scan2<<<1, 1024, 0, stream>>>(bsum, boff, nbScan);
  k_scan3<<<(N + 1 + TPB - 1) / TPB, TPB, 0, stream>>>(rp, boff, bsum, cursor, N, nbScan);
  k_fill<<<(E + TPB - 1) / TPB, TPB, 0, stream>>>(srcA, dstA, cursor, csr, E);
  k_pad<<<(N + TPB - 1) / TPB, TPB, 0, stream>>>(cursor, rp, csr, N);

  // layer 1 (F=1)
  k_agg1<<<(N + TPB - 1) / TPB, TPB, 0, stream>>>((const float4*)x, rp, deg, csr, (float4*)agg1, N);
  k_l1<<<((size_t)rows * 8 + TPB - 1) / TPB, TPB, 0, stream>>>(x, agg1, W1l, b1l, W1r, hA, rows);

  // layers 2 & 3: fused gather + dual MFMA GEMM
  int nbLayer = (N + 31) / 32;
  k_layer<<<nbLayer, TPB, 0, stream>>>(hA, rp, deg, csr, Wb2l, Wb2r, b2l, hB, N);
  k_layer<<<nbLayer, TPB, 0, stream>>>(hB, rp, deg, csr, Wb3l, Wb3r, b3l, hA, N);

  // pooling + head
  k_pool<<<512, TPB, 0, stream>>>(hA, batch, pooled, N);
  k_final<<<(B * 4 + TPB - 1) / TPB, TPB, 0, stream>>>(pooled, gcnt, Wlin, blin, out, B);
}

// Round 6
// 428.791 us; speedup vs baseline: 1.1112x; 1.1112x over previous
//
#include <hip/hip_runtime.h>
#include <math.h>

#define TPB 256

typedef unsigned short ushort_t;
typedef unsigned char uchar_t;
typedef __attribute__((ext_vector_type(8))) short short8v;     // 8 bf16 (4 VGPRs), MFMA A/B frag
typedef __attribute__((ext_vector_type(4))) float f32x4;       // MFMA C/D frag
typedef __attribute__((ext_vector_type(8))) unsigned short ushort8;

__device__ __forceinline__ float b2f(unsigned short u) {
  union { unsigned int i; float f; } c; c.i = ((unsigned int)u) << 16; return c.f;
}
__device__ __forceinline__ unsigned short f2b(float f) {
  union { float f; unsigned int i; } c; c.f = f;
  unsigned int x = c.i;
  x += 0x7FFFu + ((x >> 16) & 1u);           // round-to-nearest-even
  return (unsigned short)(x >> 16);
}

// fp8 row (8 bytes) -> bf16 MFMA half-fragment (exact: e4m3 subset of bf16)
__device__ __forceinline__ short8v fp8x8_to_bf16(const uchar_t* p) {
  uint2 u = *(const uint2*)p;
  auto p0 = __builtin_amdgcn_cvt_pk_f32_fp8(u.x, false);
  auto p1 = __builtin_amdgcn_cvt_pk_f32_fp8(u.x, true);
  auto p2 = __builtin_amdgcn_cvt_pk_f32_fp8(u.y, false);
  auto p3 = __builtin_amdgcn_cvt_pk_f32_fp8(u.y, true);
  ushort8 o;
  o[0] = f2b(p0[0]); o[1] = f2b(p0[1]); o[2] = f2b(p1[0]); o[3] = f2b(p1[1]);
  o[4] = f2b(p2[0]); o[5] = f2b(p2[1]); o[6] = f2b(p3[0]); o[7] = f2b(p3[1]);
  union { ushort8 a; short8v b; } c; c.a = o; return c.b;
}

// ---------------- CSR build (padded to multiple of 8 per node) ----------------
__global__ void k_hist(const int* __restrict__ dst, int* deg, int E) {
  int e = blockIdx.x * TPB + threadIdx.x;
  if (e < E) atomicAdd(&deg[dst[e]], 1);
}

__global__ void k_gcnt(const int* __restrict__ batch, int* gcnt, int N) {
  int t = blockIdx.x * TPB + threadIdx.x;
  int n0 = t * 16;
  if (n0 >= N) return;
  int n1 = min(n0 + 16, N);
  int cur = batch[n0];
  int c = 0;
  for (int n = n0; n < n1; ++n) {
    int b = batch[n];
    if (b != cur) { atomicAdd(&gcnt[cur], c); cur = b; c = 0; }
    ++c;
  }
  atomicAdd(&gcnt[cur], c);
}

// scan input = deg rounded up to multiple of 8
__global__ void k_scan1(const int* __restrict__ deg, int* rp, int* bsum, int N) {
  __shared__ int s[TPB];
  int t = threadIdx.x;
  int i = blockIdx.x * TPB + t;
  int v = (i < N) ? ((deg[i] + 7) & ~7) : 0;
  s[t] = v;
  __syncthreads();
  for (int d = 1; d < TPB; d <<= 1) {
    int u = (t >= d) ? s[t - d] : 0;
    __syncthreads();
    s[t] += u;
    __syncthreads();
  }
  if (i < N) rp[i] = s[t] - v;
  if (t == TPB - 1) bsum[blockIdx.x] = s[t];
}

__global__ void k_scan2(const int* bsum, int* boff, int nb) {
  __shared__ int s[1024];
  int t = threadIdx.x;
  int v = (t < nb) ? bsum[t] : 0;
  s[t] = v;
  __syncthreads();
  for (int d = 1; d < 1024; d <<= 1) {
    int u = (t >= d) ? s[t - d] : 0;
    __syncthreads();
    s[t] += u;
    __syncthreads();
  }
  if (t < nb) boff[t] = s[t] - v;
}

__global__ void k_scan3(int* rp, const int* __restrict__ boff, const int* __restrict__ bsum,
                        int* cursor, int N, int nb) {
  int i = blockIdx.x * TPB + threadIdx.x;
  if (i < N) {
    int v = rp[i] + boff[i >> 8];
    rp[i] = v;
    cursor[i] = v;
  } else if (i == N) {
    rp[N] = boff[nb - 1] + bsum[nb - 1];       // total padded edges
  }
}

__global__ void k_fill(const int* __restrict__ src, const int* __restrict__ dst,
                       int* cursor, int* __restrict__ csr, int E) {
  int e = blockIdx.x * TPB + threadIdx.x;
  if (e < E) {
    int p = atomicAdd(&cursor[dst[e]], 1);
    csr[p] = src[e];
  }
}

// fill dummy slots with index N (dedicated zero row)
__global__ void k_pad(const int* __restrict__ cursor, const int* __restrict__ rp,
                      int* __restrict__ csr, int N) {
  int n = blockIdx.x * TPB + threadIdx.x;
  if (n >= N) return;
  int c = cursor[n], e = rp[n + 1];
  for (int p = c; p < e; ++p) csr[p] = N;
}

// ---------------- weight fp32 -> bf16 ----------------
__global__ void k_cvtw(const float* __restrict__ s0, const float* __restrict__ s1,
                       const float* __restrict__ s2, const float* __restrict__ s3,
                       ushort_t* d0, ushort_t* d1, ushort_t* d2, ushort_t* d3, int n) {
  int i = blockIdx.x * TPB + threadIdx.x;
  if (i < n) { d0[i] = f2b(s0[i]); d1[i] = f2b(s1[i]); d2[i] = f2b(s2[i]); d3[i] = f2b(s3[i]); }
}

// ---------------- Layer 1 (F=1), real-edge prefix only ----------------
__global__ void k_agg1(const float4* __restrict__ x, const int* __restrict__ rp,
                       const int* __restrict__ deg, const int* __restrict__ csr,
                       float4* __restrict__ agg1, int N) {
  int n = blockIdx.x * TPB + threadIdx.x;
  if (n >= N) return;
  int b = rp[n], d = deg[n], e = b + d;
  float4 a = make_float4(0.f, 0.f, 0.f, 0.f);
  int i = b;
  for (; i + 1 < e; i += 2) {
    float4 v0 = x[csr[i]];
    float4 v1 = x[csr[i + 1]];
    a.x += v0.x + v1.x; a.y += v0.y + v1.y;
    a.z += v0.z + v1.z; a.w += v0.w + v1.w;
  }
  if (i < e) {
    float4 v = x[csr[i]];
    a.x += v.x; a.y += v.y; a.z += v.z; a.w += v.w;
  }
  float inv = (d > 0) ? 1.f / (float)d : 0.f;
  a.x *= inv; a.y *= inv; a.z *= inv; a.w *= inv;
  agg1[n] = a;
}

// h1 row r: bf16 + fp8 copies
__global__ void k_l1(const float* __restrict__ x, const float* __restrict__ agg1,
                     const float* __restrict__ W1l, const float* __restrict__ b1l,
                     const float* __restrict__ W1r, ushort_t* __restrict__ h,
                     uchar_t* __restrict__ h8, int rows) {
  int q = blockIdx.x * TPB + threadIdx.x;
  if (q >= rows * 8) return;
  int r = q >> 3, c8 = (q & 7) * 8;
  float a = agg1[r], xx = x[r];
  float vv[8];
  ushort8 o;
#pragma unroll
  for (int k = 0; k < 8; ++k) {
    vv[k] = fmaxf(a * W1l[c8 + k] + b1l[c8 + k] + xx * W1r[c8 + k], 0.f);
    o[k] = f2b(vv[k]);
  }
  *(ushort8*)(h + (size_t)r * 64 + c8) = o;
  unsigned int w0 = __builtin_amdgcn_cvt_pk_fp8_f32(vv[0], vv[1], 0u, false);
  w0 = __builtin_amdgcn_cvt_pk_fp8_f32(vv[2], vv[3], w0, true);
  unsigned int w1 = __builtin_amdgcn_cvt_pk_fp8_f32(vv[4], vv[5], 0u, false);
  w1 = __builtin_amdgcn_cvt_pk_fp8_f32(vv[6], vv[7], w1, true);
  uint2 st; st.x = w0; st.y = w1;
  *(uint2*)(h8 + (size_t)r * 64 + c8) = st;
}

// ---------------- Fused layer: fp8 gather + dual MFMA GEMM + bias + relu ----------
// Block: 256 threads = 4 waves = 32 nodes = 128 GEMM rows.
// Gather: 16 groups of 16 lanes; group owns 2 nodes; lane owns 16 features (16B fp8
// load per neighbor); csr indices staged in LDS; loop = deg_pad/8 iters (padded).
// Own-row fragments from bf16 (hInBf) or fp8 (hIn8) per layer.
#define NB1(IDX) { \
    uint4 v = *(const uint4*)(h8sl + (size_t)(IDX) * 256); \
    auto q0 = __builtin_amdgcn_cvt_pk_f32_fp8(v.x, false); \
    auto q1 = __builtin_amdgcn_cvt_pk_f32_fp8(v.x, true);  \
    auto q2 = __builtin_amdgcn_cvt_pk_f32_fp8(v.y, false); \
    auto q3 = __builtin_amdgcn_cvt_pk_f32_fp8(v.y, true);  \
    auto q4 = __builtin_amdgcn_cvt_pk_f32_fp8(v.z, false); \
    auto q5 = __builtin_amdgcn_cvt_pk_f32_fp8(v.z, true);  \
    auto q6 = __builtin_amdgcn_cvt_pk_f32_fp8(v.w, false); \
    auto q7 = __builtin_amdgcn_cvt_pk_f32_fp8(v.w, true);  \
    acc[0] += q0[0];  acc[1] += q0[1];  acc[2] += q1[0];  acc[3] += q1[1];  \
    acc[4] += q2[0];  acc[5] += q2[1];  acc[6] += q3[0];  acc[7] += q3[1];  \
    acc[8] += q4[0];  acc[9] += q4[1];  acc[10] += q5[0]; acc[11] += q5[1]; \
    acc[12] += q6[0]; acc[13] += q6[1]; acc[14] += q7[0]; acc[15] += q7[1]; }

__global__ __launch_bounds__(256) void k_layer(
    const ushort_t* __restrict__ hInBf, const uchar_t* __restrict__ hIn8,
    const int* __restrict__ rp, const int* __restrict__ deg, const int* __restrict__ csr,
    const ushort_t* __restrict__ Wlb, const ushort_t* __restrict__ Wrb,
    const float* __restrict__ bias, ushort_t* __restrict__ hOut,
    uchar_t* __restrict__ hOut8, int N) {
  __shared__ ushort_t As[8192];                 // [128 rows][64 bf16], 16B-unit XOR swizzle
  __shared__ __align__(16) int csr_s[16 * 68];  // 64-edge stage per 16-lane group
  int t = threadIdx.x;
  int wave = t >> 6, lane = t & 63;
  int g = lane >> 4, l15 = lane & 15;
  int gq = t >> 4, li = t & 15;                 // gather group / lane-in-group
  int n0 = blockIdx.x * 32;
  int r0 = blockIdx.x * 128;

  const uchar_t* h8sl = hIn8 + li * 16;         // lane's 16-feature fp8 slice

  // stage this group's csr span (2 consecutive nodes) into LDS
  int nb0 = n0 + gq * 2;
  int gb = rp[nb0];
  int cnt = rp[nb0 + 2] - gb;
  bool fits = (cnt <= 64);
  if (fits) {
    for (int i = li; i < cnt; i += 16) csr_s[gq * 68 + i] = csr[gb + i];
  }

#pragma unroll
  for (int k2 = 0; k2 < 2; ++k2) {
    int nl = gq * 2 + k2;
    int n = n0 + nl;
    int b = rp[n], e = rp[n + 1];
    float acc[16];
#pragma unroll
    for (int j = 0; j < 16; ++j) acc[j] = 0.f;

    if (fits) {
      for (int i = b - gb; i < e - gb; i += 8) {
        int4 c0 = *(const int4*)&csr_s[gq * 68 + i];
        int4 c1 = *(const int4*)&csr_s[gq * 68 + i + 4];
        NB1(c0.x) NB1(c0.y) NB1(c0.z) NB1(c0.w)
        NB1(c1.x) NB1(c1.y) NB1(c1.z) NB1(c1.w)
      }
    } else {
      for (int i = b; i < e; i += 8) {
        int4 c0 = *(const int4*)(csr + i);
        int4 c1 = *(const int4*)(csr + i + 4);
        NB1(c0.x) NB1(c0.y) NB1(c0.z) NB1(c0.w)
        NB1(c1.x) NB1(c1.y) NB1(c1.z) NB1(c1.w)
      }
    }

    int d = deg[n];
    float inv = (d > 0) ? 1.f / (float)d : 0.f;
    ushort8 pk0, pk1;
#pragma unroll
    for (int j = 0; j < 8; ++j) {
      pk0[j] = f2b(acc[j] * inv);
      pk1[j] = f2b(acc[j + 8] * inv);
    }
    int row = nl * 4 + (li >> 2);
    int cb = (li & 3) * 32;
    int xr = (row & 7) << 4;
    *(ushort8*)((char*)As + row * 128 + (cb ^ xr)) = pk0;
    *(ushort8*)((char*)As + row * 128 + ((cb + 16) ^ xr)) = pk1;
  }
  __syncthreads();

  // ---- GEMM: wave owns rows [wave*32, wave*32+32) = 2 tiles of 16 ----
  short8v af[2][2], hf[2][2];
#pragma unroll
  for (int tile = 0; tile < 2; ++tile) {
    int arow = wave * 32 + tile * 16 + l15;
    int xr = (arow & 7) << 4;
    af[tile][0] = *(const short8v*)((char*)As + arow * 128 + ((g * 16) ^ xr));
    af[tile][1] = *(const short8v*)((char*)As + arow * 128 + ((g * 16 + 64) ^ xr));
    int rbase = r0 + arow;
    if (hInBf) {
      const ushort_t* hrow = hInBf + (size_t)rbase * 64;
      hf[tile][0] = *(const short8v*)(hrow + g * 8);
      hf[tile][1] = *(const short8v*)(hrow + 32 + g * 8);
    } else {
      const uchar_t* hrow8 = hIn8 + (size_t)rbase * 64;
      hf[tile][0] = fp8x8_to_bf16(hrow8 + g * 8);
      hf[tile][1] = fp8x8_to_bf16(hrow8 + 32 + g * 8);
    }
  }

  f32x4 fac[4][2];
#pragma unroll
  for (int c = 0; c < 4; ++c) {
    float bv = bias[c * 16 + l15];
    const ushort_t* wl = Wlb + (size_t)(c * 16 + l15) * 64;
    const ushort_t* wr = Wrb + (size_t)(c * 16 + l15) * 64;
    short8v bl0 = *(const short8v*)(wl + g * 8);
    short8v bl1 = *(const short8v*)(wl + 32 + g * 8);
    short8v br0 = *(const short8v*)(wr + g * 8);
    short8v br1 = *(const short8v*)(wr + 32 + g * 8);
#pragma unroll
    for (int tile = 0; tile < 2; ++tile) {
      fac[c][tile] = (f32x4){bv, bv, bv, bv};
      fac[c][tile] = __builtin_amdgcn_mfma_f32_16x16x32_bf16(af[tile][0], bl0, fac[c][tile], 0, 0, 0);
      fac[c][tile] = __builtin_amdgcn_mfma_f32_16x16x32_bf16(af[tile][1], bl1, fac[c][tile], 0, 0, 0);
      fac[c][tile] = __builtin_amdgcn_mfma_f32_16x16x32_bf16(hf[tile][0], br0, fac[c][tile], 0, 0, 0);
      fac[c][tile] = __builtin_amdgcn_mfma_f32_16x16x32_bf16(hf[tile][1], br1, fac[c][tile], 0, 0, 0);
    }
  }

  // ---- C/D: col = lane&15, row = (lane>>4)*4 + reg ----
  bool wBf = (hOut != nullptr);
  bool wF8 = (hOut8 != nullptr);
#pragma unroll
  for (int tile = 0; tile < 2; ++tile) {
#pragma unroll
    for (int c = 0; c < 4; ++c) {
#pragma unroll
      for (int i2 = 0; i2 < 4; ++i2) {
        int grow = r0 + wave * 32 + tile * 16 + g * 4 + i2;
        float v = fmaxf(fac[c][tile][i2], 0.f);
        size_t off = (size_t)grow * 64 + c * 16 + l15;
        if (wBf) hOut[off] = f2b(v);
        if (wF8) hOut8[off] =
            (uchar_t)(__builtin_amdgcn_cvt_pk_fp8_f32(v, v, 0u, false) & 0xFF);
      }
    }
  }
}

// ---------------- Pooling (batch sorted: run-length accumulate), bf16 in ----------------
__global__ void k_pool(const ushort_t* __restrict__ h, const int* __restrict__ batch,
                       float* pooled, int N) {
  int t = threadIdx.x;
  int nPer = (N + gridDim.x - 1) / gridDim.x;
  int n0 = blockIdx.x * nPer;
  int n1 = min(N, n0 + nPer);
  if (n0 >= n1) return;
  float acc = 0.f;
  int cur = batch[n0];
  for (int n = n0; n < n1; ++n) {
    int b = batch[n];
    if (b != cur) {
      atomicAdd(&pooled[cur * 256 + t], acc);
      acc = 0.f;
      cur = b;
    }
    acc += b2f(h[(size_t)n * 256 + t]);
  }
  atomicAdd(&pooled[cur * 256 + t], acc);
}

__global__ void k_final(const float* __restrict__ pooled, const int* __restrict__ gcnt,
                        const float* __restrict__ Wlin, const float* __restrict__ blin,
                        float* __restrict__ out, int B) {
  int t = blockIdx.x * TPB + threadIdx.x;
  int b = t >> 2, j = t & 3;
  if (b >= B) return;
  float inv = 1.f / fmaxf((float)gcnt[b], 1.f);
  float s = blin[0];
  const float* p = pooled + b * 256 + j * 64;
#pragma unroll
  for (int f = 0; f < 64; ++f) s += p[f] * inv * Wlin[f];
  float z = 1.f / (1.f + expf(-s));
  z += __shfl_xor(z, 1);
  z += __shfl_xor(z, 2);
  if (j == 0) out[b] = 0.25f * z;
}

// ---------------- Host launcher ----------------
extern "C" void kernel_launch(void* const* d_in, const int* in_sizes, int n_in,
                              void* d_out, int out_size, void* d_ws, size_t ws_size,
                              hipStream_t stream) {
  const float* x   = (const float*)d_in[0];
  const int* edge  = (const int*)d_in[1];
  const int* batch = (const int*)d_in[2];
  const float* W1l = (const float*)d_in[3];
  const float* b1l = (const float*)d_in[4];
  const float* W1r = (const float*)d_in[5];
  const float* W2l = (const float*)d_in[6];
  const float* b2l = (const float*)d_in[7];
  const float* W2r = (const float*)d_in[8];
  const float* W3l = (const float*)d_in[9];
  const float* b3l = (const float*)d_in[10];
  const float* W3r = (const float*)d_in[11];
  const float* Wlin = (const float*)d_in[12];
  const float* blin = (const float*)d_in[13];
  float* out = (float*)d_out;

  const int N = in_sizes[0] / 4;          // x: [N,1,4]
  const int E = in_sizes[1] / 2;          // edge_index: [2,E]
  const int B = out_size;
  const int rows = 4 * N;

  const int* srcA = edge;
  const int* dstA = edge + E;

  // workspace carve (~113 MB total)
  char* p = (char*)d_ws;
  auto carve = [&](size_t bytes) -> void* {
    void* r = (void*)p;
    p += (bytes + 255) & ~(size_t)255;
    return r;
  };
  int* deg     = (int*)carve((size_t)N * 4);
  int* rp      = (int*)carve((size_t)(N + 1) * 4);   // padded row pointers
  int* cursor  = (int*)carve((size_t)N * 4);
  int* bsum    = (int*)carve(4096);
  int* boff    = (int*)carve(4096);
  int* gcnt    = (int*)carve((size_t)B * 4);
  int* csr     = (int*)carve(((size_t)E + 8 * (size_t)N) * 4);
  float* agg1  = (float*)carve((size_t)N * 4 * 4);
  float* pooled = (float*)carve((size_t)B * 256 * 4);
  ushort_t* Wb2l = (ushort_t*)carve(4096 * 2);
  ushort_t* Wb2r = (ushort_t*)carve(4096 * 2);
  ushort_t* Wb3l = (ushort_t*)carve(4096 * 2);
  ushort_t* Wb3r = (ushort_t*)carve(4096 * 2);
  ushort_t* hA  = (ushort_t*)carve(((size_t)N + 1) * 256 * 2);  // bf16 h1 / h3
  uchar_t* hA8  = (uchar_t*)carve(((size_t)N + 1) * 256);       // fp8 h1
  uchar_t* hB8  = (uchar_t*)carve(((size_t)N + 1) * 256);       // fp8 h2
  (void)ws_size; (void)n_in;

  hipMemsetAsync(deg, 0, (size_t)N * 4, stream);
  hipMemsetAsync(gcnt, 0, (size_t)B * 4, stream);
  hipMemsetAsync(pooled, 0, (size_t)B * 256 * 4, stream);
  hipMemsetAsync(hA8 + (size_t)N * 256, 0, 256, stream);        // fp8 zero rows
  hipMemsetAsync(hB8 + (size_t)N * 256, 0, 256, stream);

  int nbScan = (N + TPB - 1) / TPB;

  k_hist<<<(E + TPB - 1) / TPB, TPB, 0, stream>>>(dstA, deg, E);
  k_gcnt<<<((N + 15) / 16 + TPB - 1) / TPB, TPB, 0, stream>>>(batch, gcnt, N);
  k_cvtw<<<16, TPB, 0, stream>>>(W2l, W2r, W3l, W3r, Wb2l, Wb2r, Wb3l, Wb3r, 4096);
  k_scan1<<<nbScan, TPB, 0, stream>>>(deg, rp, bsum, N);
  k_scan2<<<1, 1024, 0, stream>>>(bsum, boff, nbScan);
  k_scan3<<<(N + 1 + TPB - 1) / TPB, TPB, 0, stream>>>(rp, boff, bsum, cursor, N, nbScan);
  k_fill<<<(E + TPB - 1) / TPB, TPB, 0, stream>>>(srcA, dstA, cursor, csr, E);
  k_pad<<<(N + TPB - 1) / TPB, TPB, 0, stream>>>(cursor, rp, csr, N);

  // layer 1 (F=1)
  k_agg1<<<(N + TPB - 1) / TPB, TPB, 0, stream>>>((const float4*)x, rp, deg, csr, (float4*)agg1, N);
  k_l1<<<((size_t)rows * 8 + TPB - 1) / TPB, TPB, 0, stream>>>(x, agg1, W1l, b1l, W1r, hA, hA8, rows);

  // layers 2 & 3: fused fp8 gather + dual MFMA GEMM
  int nbLayer = (N + 31) / 32;
  k_layer<<<nbLayer, TPB, 0, stream>>>(hA, hA8, rp, deg, csr, Wb2l, Wb2r, b2l,
                                       (ushort_t*)nullptr, hB8, N);
  k_layer<<<nbLayer, TPB, 0, stream>>>((const ushort_t*)nullptr, hB8, rp, deg, csr,
                                       Wb3l, Wb3r, b3l, hA, (uchar_t*)nullptr, N);

  // pooling + head
  k_pool<<<512, TPB, 0, stream>>>(hA, batch, pooled, N);
  k_final<<<(B * 4 + TPB - 1) / TPB, TPB, 0, stream>>>(pooled, gcnt, Wlin, blin, out, B);
}

// Round 7
// 381.605 us; speedup vs baseline: 1.2486x; 1.1237x over previous
//
#include <hip/hip_runtime.h>
#include <math.h>

#define TPB 256

typedef unsigned short ushort_t;
typedef unsigned char uchar_t;
typedef __attribute__((ext_vector_type(8))) short short8v;     // 8 bf16 (4 VGPRs), MFMA A/B frag
typedef __attribute__((ext_vector_type(4))) float f32x4;       // MFMA C/D frag
typedef __attribute__((ext_vector_type(8))) unsigned short ushort8;

__device__ __forceinline__ float b2f(unsigned short u) {
  union { unsigned int i; float f; } c; c.i = ((unsigned int)u) << 16; return c.f;
}
__device__ __forceinline__ unsigned short f2b(float f) {
  union { float f; unsigned int i; } c; c.f = f;
  unsigned int x = c.i;
  x += 0x7FFFu + ((x >> 16) & 1u);           // round-to-nearest-even
  return (unsigned short)(x >> 16);
}

// fp8 row (8 bytes) -> bf16 MFMA half-fragment (exact: e4m3 subset of bf16)
__device__ __forceinline__ short8v fp8x8_to_bf16(const uchar_t* p) {
  uint2 u = *(const uint2*)p;
  auto p0 = __builtin_amdgcn_cvt_pk_f32_fp8(u.x, false);
  auto p1 = __builtin_amdgcn_cvt_pk_f32_fp8(u.x, true);
  auto p2 = __builtin_amdgcn_cvt_pk_f32_fp8(u.y, false);
  auto p3 = __builtin_amdgcn_cvt_pk_f32_fp8(u.y, true);
  ushort8 o;
  o[0] = f2b(p0[0]); o[1] = f2b(p0[1]); o[2] = f2b(p1[0]); o[3] = f2b(p1[1]);
  o[4] = f2b(p2[0]); o[5] = f2b(p2[1]); o[6] = f2b(p3[0]); o[7] = f2b(p3[1]);
  union { ushort8 a; short8v b; } c; c.a = o; return c.b;
}

// ---------------- CSR build (padded to multiple of 8 per node) ----------------
__global__ void k_hist(const int* __restrict__ dst, int* deg, int E) {
  int e = blockIdx.x * TPB + threadIdx.x;
  if (e < E) atomicAdd(&deg[dst[e]], 1);
}

__global__ void k_gcnt(const int* __restrict__ batch, int* gcnt, int N) {
  int t = blockIdx.x * TPB + threadIdx.x;
  int n0 = t * 16;
  if (n0 >= N) return;
  int n1 = min(n0 + 16, N);
  int cur = batch[n0];
  int c = 0;
  for (int n = n0; n < n1; ++n) {
    int b = batch[n];
    if (b != cur) { atomicAdd(&gcnt[cur], c); cur = b; c = 0; }
    ++c;
  }
  atomicAdd(&gcnt[cur], c);
}

// scan input = deg rounded up to multiple of 8
__global__ void k_scan1(const int* __restrict__ deg, int* rp, int* bsum, int N) {
  __shared__ int s[TPB];
  int t = threadIdx.x;
  int i = blockIdx.x * TPB + t;
  int v = (i < N) ? ((deg[i] + 7) & ~7) : 0;
  s[t] = v;
  __syncthreads();
  for (int d = 1; d < TPB; d <<= 1) {
    int u = (t >= d) ? s[t - d] : 0;
    __syncthreads();
    s[t] += u;
    __syncthreads();
  }
  if (i < N) rp[i] = s[t] - v;
  if (t == TPB - 1) bsum[blockIdx.x] = s[t];
}

__global__ void k_scan2(const int* bsum, int* boff, int nb) {
  __shared__ int s[1024];
  int t = threadIdx.x;
  int v = (t < nb) ? bsum[t] : 0;
  s[t] = v;
  __syncthreads();
  for (int d = 1; d < 1024; d <<= 1) {
    int u = (t >= d) ? s[t - d] : 0;
    __syncthreads();
    s[t] += u;
    __syncthreads();
  }
  if (t < nb) boff[t] = s[t] - v;
}

__global__ void k_scan3(int* rp, const int* __restrict__ boff, const int* __restrict__ bsum,
                        int* cursor, int N, int nb) {
  int i = blockIdx.x * TPB + threadIdx.x;
  if (i < N) {
    int v = rp[i] + boff[i >> 8];
    rp[i] = v;
    cursor[i] = v;
  } else if (i == N) {
    rp[N] = boff[nb - 1] + bsum[nb - 1];       // total padded edges
  }
}

__global__ void k_fill(const int* __restrict__ src, const int* __restrict__ dst,
                       int* cursor, int* __restrict__ csr, int E) {
  int e = blockIdx.x * TPB + threadIdx.x;
  if (e < E) {
    int p = atomicAdd(&cursor[dst[e]], 1);
    csr[p] = src[e];
  }
}

// fill dummy slots with index N (dedicated zero row)
__global__ void k_pad(const int* __restrict__ cursor, const int* __restrict__ rp,
                      int* __restrict__ csr, int N) {
  int n = blockIdx.x * TPB + threadIdx.x;
  if (n >= N) return;
  int c = cursor[n], e = rp[n + 1];
  for (int p = c; p < e; ++p) csr[p] = N;
}

// ---------------- weight fp32 -> bf16 ----------------
__global__ void k_cvtw(const float* __restrict__ s0, const float* __restrict__ s1,
                       const float* __restrict__ s2, const float* __restrict__ s3,
                       ushort_t* d0, ushort_t* d1, ushort_t* d2, ushort_t* d3, int n) {
  int i = blockIdx.x * TPB + threadIdx.x;
  if (i < n) { d0[i] = f2b(s0[i]); d1[i] = f2b(s1[i]); d2[i] = f2b(s2[i]); d3[i] = f2b(s3[i]); }
}

// ---------------- Layer 1 (F=1), padded span, 8 loads in flight ----------------
__global__ void k_agg1(const float4* __restrict__ x, const int* __restrict__ rp,
                       const int* __restrict__ deg, const int* __restrict__ csr,
                       float4* __restrict__ agg1, int N) {
  int n = blockIdx.x * TPB + threadIdx.x;
  if (n >= N) return;
  int b = rp[n], e = rp[n + 1];
  float4 a = make_float4(0.f, 0.f, 0.f, 0.f);
  for (int i = b; i < e; i += 8) {
    int4 c0 = *(const int4*)(csr + i);
    int4 c1 = *(const int4*)(csr + i + 4);
    int id[8] = {c0.x, c0.y, c0.z, c0.w, c1.x, c1.y, c1.z, c1.w};
#pragma unroll
    for (int j = 0; j < 8; ++j) {
      float4 v = x[min(id[j], N - 1)];
      float m = (id[j] < N) ? 1.f : 0.f;
      a.x += v.x * m; a.y += v.y * m; a.z += v.z * m; a.w += v.w * m;
    }
  }
  int d = deg[n];
  float inv = (d > 0) ? 1.f / (float)d : 0.f;
  a.x *= inv; a.y *= inv; a.z *= inv; a.w *= inv;
  agg1[n] = a;
}

// h1 row r: bf16 + fp8 copies
__global__ void k_l1(const float* __restrict__ x, const float* __restrict__ agg1,
                     const float* __restrict__ W1l, const float* __restrict__ b1l,
                     const float* __restrict__ W1r, ushort_t* __restrict__ h,
                     uchar_t* __restrict__ h8, int rows) {
  int q = blockIdx.x * TPB + threadIdx.x;
  if (q >= rows * 8) return;
  int r = q >> 3, c8 = (q & 7) * 8;
  float a = agg1[r], xx = x[r];
  float vv[8];
  ushort8 o;
#pragma unroll
  for (int k = 0; k < 8; ++k) {
    vv[k] = fmaxf(a * W1l[c8 + k] + b1l[c8 + k] + xx * W1r[c8 + k], 0.f);
    o[k] = f2b(vv[k]);
  }
  *(ushort8*)(h + (size_t)r * 64 + c8) = o;
  unsigned int w0 = __builtin_amdgcn_cvt_pk_fp8_f32(vv[0], vv[1], 0u, false);
  w0 = __builtin_amdgcn_cvt_pk_fp8_f32(vv[2], vv[3], w0, true);
  unsigned int w1 = __builtin_amdgcn_cvt_pk_fp8_f32(vv[4], vv[5], 0u, false);
  w1 = __builtin_amdgcn_cvt_pk_fp8_f32(vv[6], vv[7], w1, true);
  uint2 st; st.x = w0; st.y = w1;
  *(uint2*)(h8 + (size_t)r * 64 + c8) = st;
}

// ---------------- Fused layer: fp8 gather + dual MFMA GEMM + bias + relu ----------
// Block: 256 threads = 4 waves = 32 nodes = 128 GEMM rows.
// Gather: 16 groups of 16 lanes; group owns 2 nodes INTERLEAVED (16 x 16B fp8 loads
// in flight per lane); per-node predicates select dummy row N (zeros) instead of
// branching; csr indices staged in LDS (span <= 64) else read from global.
#define NB8(ACC, IDX) { \
    uint4 v = *(const uint4*)(h8sl + (size_t)(IDX) * 256); \
    auto q0 = __builtin_amdgcn_cvt_pk_f32_fp8(v.x, false); \
    auto q1 = __builtin_amdgcn_cvt_pk_f32_fp8(v.x, true);  \
    auto q2 = __builtin_amdgcn_cvt_pk_f32_fp8(v.y, false); \
    auto q3 = __builtin_amdgcn_cvt_pk_f32_fp8(v.y, true);  \
    auto q4 = __builtin_amdgcn_cvt_pk_f32_fp8(v.z, false); \
    auto q5 = __builtin_amdgcn_cvt_pk_f32_fp8(v.z, true);  \
    auto q6 = __builtin_amdgcn_cvt_pk_f32_fp8(v.w, false); \
    auto q7 = __builtin_amdgcn_cvt_pk_f32_fp8(v.w, true);  \
    ACC[0] += q0[0];  ACC[1] += q0[1];  ACC[2] += q1[0];  ACC[3] += q1[1];  \
    ACC[4] += q2[0];  ACC[5] += q2[1];  ACC[6] += q3[0];  ACC[7] += q3[1];  \
    ACC[8] += q4[0];  ACC[9] += q4[1];  ACC[10] += q5[0]; ACC[11] += q5[1]; \
    ACC[12] += q6[0]; ACC[13] += q6[1]; ACC[14] += q7[0]; ACC[15] += q7[1]; }

__global__ __launch_bounds__(256) void k_layer(
    const ushort_t* __restrict__ hInBf, const uchar_t* __restrict__ hIn8,
    const int* __restrict__ rp, const int* __restrict__ deg, const int* __restrict__ csr,
    const ushort_t* __restrict__ Wlb, const ushort_t* __restrict__ Wrb,
    const float* __restrict__ bias, ushort_t* __restrict__ hOut,
    uchar_t* __restrict__ hOut8, int N) {
  __shared__ ushort_t As[8192];                 // [128 rows][64 bf16], 16B-unit XOR swizzle
  __shared__ __align__(16) int csr_s[16 * 68];  // 64-edge stage per 16-lane group
  int t = threadIdx.x;
  int wave = t >> 6, lane = t & 63;
  int g = lane >> 4, l15 = lane & 15;
  int gq = t >> 4, li = t & 15;                 // gather group / lane-in-group
  int n0 = blockIdx.x * 32;
  int r0 = blockIdx.x * 128;

  const uchar_t* h8sl = hIn8 + li * 16;         // lane's 16-feature fp8 slice

  // group's two nodes
  int nA = n0 + gq * 2;
  int gb = rp[nA];
  int eAabs = rp[nA + 1];
  int cnt = rp[nA + 2] - gb;
  bool fits = (cnt <= 64);
  if (fits) {
    for (int i = li; i < cnt; i += 16) csr_s[gq * 68 + i] = csr[gb + i];
  }

  int eA = eAabs - gb;                          // relative spans: A=[0,eA), B=[eA,cnt)
  int itA = eA >> 3;
  int itB = (cnt - eA) >> 3;
  int itM = max(itA, itB);
  int oCap = max(cnt - 8, 0);

  float accA[16], accB[16];
#pragma unroll
  for (int j = 0; j < 16; ++j) { accA[j] = 0.f; accB[j] = 0.f; }

  for (int it = 0; it < itM; ++it) {
    int oA = min(8 * min(it, max(itA - 1, 0)), oCap);
    int oB = min(eA + 8 * min(it, max(itB - 1, 0)), oCap);
    bool vA = it < itA, vB = it < itB;
    int4 a0, a1, b0, b1;
    if (fits) {
      a0 = *(const int4*)&csr_s[gq * 68 + oA];
      a1 = *(const int4*)&csr_s[gq * 68 + oA + 4];
      b0 = *(const int4*)&csr_s[gq * 68 + oB];
      b1 = *(const int4*)&csr_s[gq * 68 + oB + 4];
    } else {
      a0 = *(const int4*)(csr + gb + oA);
      a1 = *(const int4*)(csr + gb + oA + 4);
      b0 = *(const int4*)(csr + gb + oB);
      b1 = *(const int4*)(csr + gb + oB + 4);
    }
    if (!vA) { a0 = make_int4(N, N, N, N); a1 = a0; }
    if (!vB) { b0 = make_int4(N, N, N, N); b1 = b0; }
    NB8(accA, a0.x) NB8(accA, a0.y) NB8(accA, a0.z) NB8(accA, a0.w)
    NB8(accA, a1.x) NB8(accA, a1.y) NB8(accA, a1.z) NB8(accA, a1.w)
    NB8(accB, b0.x) NB8(accB, b0.y) NB8(accB, b0.z) NB8(accB, b0.w)
    NB8(accB, b1.x) NB8(accB, b1.y) NB8(accB, b1.z) NB8(accB, b1.w)
  }

  // finalize both nodes -> LDS A tile
#pragma unroll
  for (int k2 = 0; k2 < 2; ++k2) {
    int n = nA + k2;
    int d = deg[n];
    float inv = (d > 0) ? 1.f / (float)d : 0.f;
    float* acc = k2 ? accB : accA;
    ushort8 pk0, pk1;
#pragma unroll
    for (int j = 0; j < 8; ++j) {
      pk0[j] = f2b(acc[j] * inv);
      pk1[j] = f2b(acc[j + 8] * inv);
    }
    int nl = gq * 2 + k2;
    int row = nl * 4 + (li >> 2);
    int cb = (li & 3) * 32;
    int xr = (row & 7) << 4;
    *(ushort8*)((char*)As + row * 128 + (cb ^ xr)) = pk0;
    *(ushort8*)((char*)As + row * 128 + ((cb + 16) ^ xr)) = pk1;
  }
  __syncthreads();

  // ---- GEMM: wave owns rows [wave*32, wave*32+32) = 2 tiles of 16 ----
  short8v af[2][2], hf[2][2];
#pragma unroll
  for (int tile = 0; tile < 2; ++tile) {
    int arow = wave * 32 + tile * 16 + l15;
    int xr = (arow & 7) << 4;
    af[tile][0] = *(const short8v*)((char*)As + arow * 128 + ((g * 16) ^ xr));
    af[tile][1] = *(const short8v*)((char*)As + arow * 128 + ((g * 16 + 64) ^ xr));
    int rbase = r0 + arow;
    if (hInBf) {
      const ushort_t* hrow = hInBf + (size_t)rbase * 64;
      hf[tile][0] = *(const short8v*)(hrow + g * 8);
      hf[tile][1] = *(const short8v*)(hrow + 32 + g * 8);
    } else {
      const uchar_t* hrow8 = hIn8 + (size_t)rbase * 64;
      hf[tile][0] = fp8x8_to_bf16(hrow8 + g * 8);
      hf[tile][1] = fp8x8_to_bf16(hrow8 + 32 + g * 8);
    }
  }

  f32x4 fac[4][2];
#pragma unroll
  for (int c = 0; c < 4; ++c) {
    float bv = bias[c * 16 + l15];
    const ushort_t* wl = Wlb + (size_t)(c * 16 + l15) * 64;
    const ushort_t* wr = Wrb + (size_t)(c * 16 + l15) * 64;
    short8v bl0 = *(const short8v*)(wl + g * 8);
    short8v bl1 = *(const short8v*)(wl + 32 + g * 8);
    short8v br0 = *(const short8v*)(wr + g * 8);
    short8v br1 = *(const short8v*)(wr + 32 + g * 8);
#pragma unroll
    for (int tile = 0; tile < 2; ++tile) {
      fac[c][tile] = (f32x4){bv, bv, bv, bv};
      fac[c][tile] = __builtin_amdgcn_mfma_f32_16x16x32_bf16(af[tile][0], bl0, fac[c][tile], 0, 0, 0);
      fac[c][tile] = __builtin_amdgcn_mfma_f32_16x16x32_bf16(af[tile][1], bl1, fac[c][tile], 0, 0, 0);
      fac[c][tile] = __builtin_amdgcn_mfma_f32_16x16x32_bf16(hf[tile][0], br0, fac[c][tile], 0, 0, 0);
      fac[c][tile] = __builtin_amdgcn_mfma_f32_16x16x32_bf16(hf[tile][1], br1, fac[c][tile], 0, 0, 0);
    }
  }

  // ---- C/D: col = lane&15, row = (lane>>4)*4 + reg ----
  bool wBf = (hOut != nullptr);
  bool wF8 = (hOut8 != nullptr);
#pragma unroll
  for (int tile = 0; tile < 2; ++tile) {
#pragma unroll
    for (int c = 0; c < 4; ++c) {
#pragma unroll
      for (int i2 = 0; i2 < 4; ++i2) {
        int grow = r0 + wave * 32 + tile * 16 + g * 4 + i2;
        float v = fmaxf(fac[c][tile][i2], 0.f);
        size_t off = (size_t)grow * 64 + c * 16 + l15;
        if (wBf) hOut[off] = f2b(v);
        if (wF8) hOut8[off] =
            (uchar_t)(__builtin_amdgcn_cvt_pk_fp8_f32(v, v, 0u, false) & 0xFF);
      }
    }
  }
}

// ---------------- Pooling (batch sorted), 4-node unroll ----------------
__global__ void k_pool(const ushort_t* __restrict__ h, const int* __restrict__ batch,
                       float* pooled, int N) {
  int t = threadIdx.x;
  int nPer = (N + gridDim.x - 1) / gridDim.x;
  int n0 = blockIdx.x * nPer;
  int n1 = min(N, n0 + nPer);
  if (n0 >= n1) return;
  float acc = 0.f;
  int cur = batch[n0];
  int n = n0;
  for (; n + 3 < n1; n += 4) {
    int b0 = batch[n], b3 = batch[n + 3];
    float v0 = b2f(h[(size_t)n * 256 + t]);
    float v1 = b2f(h[(size_t)(n + 1) * 256 + t]);
    float v2 = b2f(h[(size_t)(n + 2) * 256 + t]);
    float v3 = b2f(h[(size_t)(n + 3) * 256 + t]);
    if (b0 == b3) {
      if (b0 != cur) { atomicAdd(&pooled[cur * 256 + t], acc); acc = 0.f; cur = b0; }
      acc += (v0 + v1) + (v2 + v3);
    } else {
      int bb1 = batch[n + 1], bb2 = batch[n + 2];
      int bb[4] = {b0, bb1, bb2, b3};
      float vv[4] = {v0, v1, v2, v3};
#pragma unroll
      for (int j = 0; j < 4; ++j) {
        if (bb[j] != cur) { atomicAdd(&pooled[cur * 256 + t], acc); acc = 0.f; cur = bb[j]; }
        acc += vv[j];
      }
    }
  }
  for (; n < n1; ++n) {
    int b = batch[n];
    if (b != cur) { atomicAdd(&pooled[cur * 256 + t], acc); acc = 0.f; cur = b; }
    acc += b2f(h[(size_t)n * 256 + t]);
  }
  atomicAdd(&pooled[cur * 256 + t], acc);
}

__global__ void k_final(const float* __restrict__ pooled, const int* __restrict__ gcnt,
                        const float* __restrict__ Wlin, const float* __restrict__ blin,
                        float* __restrict__ out, int B) {
  int t = blockIdx.x * TPB + threadIdx.x;
  int b = t >> 2, j = t & 3;
  if (b >= B) return;
  float inv = 1.f / fmaxf((float)gcnt[b], 1.f);
  float s = blin[0];
  const float* p = pooled + b * 256 + j * 64;
#pragma unroll
  for (int f = 0; f < 64; ++f) s += p[f] * inv * Wlin[f];
  float z = 1.f / (1.f + expf(-s));
  z += __shfl_xor(z, 1);
  z += __shfl_xor(z, 2);
  if (j == 0) out[b] = 0.25f * z;
}

// ---------------- Host launcher ----------------
extern "C" void kernel_launch(void* const* d_in, const int* in_sizes, int n_in,
                              void* d_out, int out_size, void* d_ws, size_t ws_size,
                              hipStream_t stream) {
  const float* x   = (const float*)d_in[0];
  const int* edge  = (const int*)d_in[1];
  const int* batch = (const int*)d_in[2];
  const float* W1l = (const float*)d_in[3];
  const float* b1l = (const float*)d_in[4];
  const float* W1r = (const float*)d_in[5];
  const float* W2l = (const float*)d_in[6];
  const float* b2l = (const float*)d_in[7];
  const float* W2r = (const float*)d_in[8];
  const float* W3l = (const float*)d_in[9];
  const float* b3l = (const float*)d_in[10];
  const float* W3r = (const float*)d_in[11];
  const float* Wlin = (const float*)d_in[12];
  const float* blin = (const float*)d_in[13];
  float* out = (float*)d_out;

  const int N = in_sizes[0] / 4;          // x: [N,1,4]
  const int E = in_sizes[1] / 2;          // edge_index: [2,E]
  const int B = out_size;
  const int rows = 4 * N;

  const int* srcA = edge;
  const int* dstA = edge + E;

  // workspace carve (~113 MB total)
  char* p = (char*)d_ws;
  auto carve = [&](size_t bytes) -> void* {
    void* r = (void*)p;
    p += (bytes + 255) & ~(size_t)255;
    return r;
  };
  int* deg     = (int*)carve((size_t)N * 4);
  int* rp      = (int*)carve((size_t)(N + 1) * 4);   // padded row pointers
  int* cursor  = (int*)carve((size_t)N * 4);
  int* bsum    = (int*)carve(4096);
  int* boff    = (int*)carve(4096);
  int* gcnt    = (int*)carve((size_t)B * 4);
  int* csr     = (int*)carve(((size_t)E + 8 * (size_t)N) * 4);
  float* agg1  = (float*)carve((size_t)N * 4 * 4);
  float* pooled = (float*)carve((size_t)B * 256 * 4);
  ushort_t* Wb2l = (ushort_t*)carve(4096 * 2);
  ushort_t* Wb2r = (ushort_t*)carve(4096 * 2);
  ushort_t* Wb3l = (ushort_t*)carve(4096 * 2);
  ushort_t* Wb3r = (ushort_t*)carve(4096 * 2);
  ushort_t* hA  = (ushort_t*)carve(((size_t)N + 1) * 256 * 2);  // bf16 h1 / h3
  uchar_t* hA8  = (uchar_t*)carve(((size_t)N + 1) * 256);       // fp8 h1
  uchar_t* hB8  = (uchar_t*)carve(((size_t)N + 1) * 256);       // fp8 h2
  (void)ws_size; (void)n_in;

  hipMemsetAsync(deg, 0, (size_t)N * 4, stream);
  hipMemsetAsync(gcnt, 0, (size_t)B * 4, stream);
  hipMemsetAsync(pooled, 0, (size_t)B * 256 * 4, stream);
  hipMemsetAsync(hA8 + (size_t)N * 256, 0, 256, stream);        // fp8 zero rows
  hipMemsetAsync(hB8 + (size_t)N * 256, 0, 256, stream);

  int nbScan = (N + TPB - 1) / TPB;

  k_hist<<<(E + TPB - 1) / TPB, TPB, 0, stream>>>(dstA, deg, E);
  k_gcnt<<<((N + 15) / 16 + TPB - 1) / TPB, TPB, 0, stream>>>(batch, gcnt, N);
  k_cvtw<<<16, TPB, 0, stream>>>(W2l, W2r, W3l, W3r, Wb2l, Wb2r, Wb3l, Wb3r, 4096);
  k_scan1<<<nbScan, TPB, 0, stream>>>(deg, rp, bsum, N);
  k_scan2<<<1, 1024, 0, stream>>>(bsum, boff, nbScan);
  k_scan3<<<(N + 1 + TPB - 1) / TPB, TPB, 0, stream>>>(rp, boff, bsum, cursor, N, nbScan);
  k_fill<<<(E + TPB - 1) / TPB, TPB, 0, stream>>>(srcA, dstA, cursor, csr, E);
  k_pad<<<(N + TPB - 1) / TPB, TPB, 0, stream>>>(cursor, rp, csr, N);

  // layer 1 (F=1)
  k_agg1<<<(N + TPB - 1) / TPB, TPB, 0, stream>>>((const float4*)x, rp, deg, csr, (float4*)agg1, N);
  k_l1<<<((size_t)rows * 8 + TPB - 1) / TPB, TPB, 0, stream>>>(x, agg1, W1l, b1l, W1r, hA, hA8, rows);

  // layers 2 & 3: fused fp8 gather + dual MFMA GEMM
  int nbLayer = (N + 31) / 32;
  k_layer<<<nbLayer, TPB, 0, stream>>>(hA, hA8, rp, deg, csr, Wb2l, Wb2r, b2l,
                                       (ushort_t*)nullptr, hB8, N);
  k_layer<<<nbLayer, TPB, 0, stream>>>((const ushort_t*)nullptr, hB8, rp, deg, csr,
                                       Wb3l, Wb3r, b3l, hA, (uchar_t*)nullptr, N);

  // pooling + head
  k_pool<<<1024, TPB, 0, stream>>>(hA, batch, pooled, N);
  k_final<<<(B * 4 + TPB - 1) / TPB, TPB, 0, stream>>>(pooled, gcnt, Wlin, blin, out, B);
}

// Round 8
// 363.284 us; speedup vs baseline: 1.3116x; 1.0504x over previous
//
#include <hip/hip_runtime.h>
#include <math.h>

#define TPB 256

typedef unsigned short ushort_t;
typedef unsigned char uchar_t;
typedef __attribute__((ext_vector_type(8))) short short8v;     // 8 bf16 (4 VGPRs), MFMA A/B frag
typedef __attribute__((ext_vector_type(4))) float f32x4;       // MFMA C/D frag
typedef __attribute__((ext_vector_type(8))) unsigned short ushort8;

__device__ __forceinline__ unsigned short f2b(float f) {
  union { float f; unsigned int i; } c; c.f = f;
  unsigned int x = c.i;
  x += 0x7FFFu + ((x >> 16) & 1u);           // round-to-nearest-even
  return (unsigned short)(x >> 16);
}
__device__ __forceinline__ float b2f(unsigned short u) {
  union { unsigned int i; float f; } c; c.i = ((unsigned int)u) << 16; return c.f;
}

// fp8 row (8 bytes) -> bf16 MFMA half-fragment (exact: e4m3 subset of bf16)
__device__ __forceinline__ short8v fp8x8_to_bf16(const uchar_t* p) {
  uint2 u = *(const uint2*)p;
  auto p0 = __builtin_amdgcn_cvt_pk_f32_fp8(u.x, false);
  auto p1 = __builtin_amdgcn_cvt_pk_f32_fp8(u.x, true);
  auto p2 = __builtin_amdgcn_cvt_pk_f32_fp8(u.y, false);
  auto p3 = __builtin_amdgcn_cvt_pk_f32_fp8(u.y, true);
  ushort8 o;
  o[0] = f2b(p0[0]); o[1] = f2b(p0[1]); o[2] = f2b(p1[0]); o[3] = f2b(p1[1]);
  o[4] = f2b(p2[0]); o[5] = f2b(p2[1]); o[6] = f2b(p3[0]); o[7] = f2b(p3[1]);
  union { ushort8 a; short8v b; } c; c.a = o; return c.b;
}

// ---------------- hist (in-degree) + per-graph node counts ----------------
__global__ void k_histg(const int* __restrict__ dst, int* deg,
                        const int* __restrict__ batch, int* gcnt, int E, int N) {
  int t = blockIdx.x * TPB + threadIdx.x;
  if (t < E) atomicAdd(&deg[dst[t]], 1);
  int n0 = t * 16;
  if (n0 < N) {
    int n1 = min(n0 + 16, N);
    int cur = batch[n0];
    int c = 0;
    for (int n = n0; n < n1; ++n) {
      int b = batch[n];
      if (b != cur) { atomicAdd(&gcnt[cur], c); cur = b; c = 0; }
      ++c;
    }
    atomicAdd(&gcnt[cur], c);
  }
}

// scan input = deg rounded up to multiple of 8
__global__ void k_scan1(const int* __restrict__ deg, int* rp, int* bsum, int N) {
  __shared__ int s[TPB];
  int t = threadIdx.x;
  int i = blockIdx.x * TPB + t;
  int v = (i < N) ? ((deg[i] + 7) & ~7) : 0;
  s[t] = v;
  __syncthreads();
  for (int d = 1; d < TPB; d <<= 1) {
    int u = (t >= d) ? s[t - d] : 0;
    __syncthreads();
    s[t] += u;
    __syncthreads();
  }
  if (i < N) rp[i] = s[t] - v;
  if (t == TPB - 1) bsum[blockIdx.x] = s[t];
}

__global__ void k_scan2(const int* bsum, int* boff, int nb) {
  __shared__ int s[1024];
  int t = threadIdx.x;
  int v = (t < nb) ? bsum[t] : 0;
  s[t] = v;
  __syncthreads();
  for (int d = 1; d < 1024; d <<= 1) {
    int u = (t >= d) ? s[t - d] : 0;
    __syncthreads();
    s[t] += u;
    __syncthreads();
  }
  if (t < nb) boff[t] = s[t] - v;
}

__global__ void k_scan3(int* rp, const int* __restrict__ boff, const int* __restrict__ bsum,
                        int* cursor, int N, int nb) {
  int i = blockIdx.x * TPB + threadIdx.x;
  if (i < N) {
    int v = rp[i] + boff[i >> 8];
    rp[i] = v;
    cursor[i] = v;
  } else if (i == N) {
    rp[N] = boff[nb - 1] + bsum[nb - 1];       // total padded edges
  }
}

__global__ void k_fill(const int* __restrict__ src, const int* __restrict__ dst,
                       int* cursor, int* __restrict__ csr, int E) {
  int e = blockIdx.x * TPB + threadIdx.x;
  if (e < E) {
    int p = atomicAdd(&cursor[dst[e]], 1);
    csr[p] = src[e];
  }
}

// ---------------- weight fp32 -> bf16 (+ zero-row init for dummy edges) --------
__global__ void k_cvtw(const float* __restrict__ s0, const float* __restrict__ s1,
                       const float* __restrict__ s2, const float* __restrict__ s3,
                       ushort_t* d0, ushort_t* d1, ushort_t* d2, ushort_t* d3,
                       uchar_t* zr0, uchar_t* zr1, int n) {
  int i = blockIdx.x * TPB + threadIdx.x;
  if (i < n) { d0[i] = f2b(s0[i]); d1[i] = f2b(s1[i]); d2[i] = f2b(s2[i]); d3[i] = f2b(s3[i]); }
  if (blockIdx.x == 0) {
    if (threadIdx.x < 64) ((int*)zr0)[threadIdx.x] = 0;
    else if (threadIdx.x < 128) ((int*)zr1)[threadIdx.x - 64] = 0;
  }
}

// ---------------- Layer 1 agg (F=1) + CSR dummy padding ----------------
__global__ void k_agg1(const float4* __restrict__ x, const int* __restrict__ rp,
                       const int* __restrict__ deg, const int* __restrict__ cursor,
                       int* __restrict__ csr, float4* __restrict__ agg1, int N) {
  int n = blockIdx.x * TPB + threadIdx.x;
  if (n >= N) return;
  int b = rp[n], e = rp[n + 1];
  float4 a = make_float4(0.f, 0.f, 0.f, 0.f);
  for (int i = b; i < e; i += 8) {
    int4 c0 = *(const int4*)(csr + i);
    int4 c1 = *(const int4*)(csr + i + 4);
    int id[8] = {c0.x, c0.y, c0.z, c0.w, c1.x, c1.y, c1.z, c1.w};
#pragma unroll
    for (int j = 0; j < 8; ++j) {
      unsigned idx = min((unsigned)id[j], (unsigned)(N - 1));  // clamp garbage/dummy
      float m = ((unsigned)id[j] < (unsigned)N) ? 1.f : 0.f;
      float4 v = x[idx];
      a.x += v.x * m; a.y += v.y * m; a.z += v.z * m; a.w += v.w * m;
    }
  }
  int d = deg[n];
  float inv = (d > 0) ? 1.f / (float)d : 0.f;
  a.x *= inv; a.y *= inv; a.z *= inv; a.w *= inv;
  agg1[n] = a;
  // pad this node's dummy CSR slots with N (zero row) for k_layer
  int c = cursor[n];
  for (int p2 = c; p2 < e; ++p2) csr[p2] = N;
}

// h1 row r (fp8 only): relu(agg1[r]*W1l[c] + b1l[c] + x[r]*W1r[c])
__global__ void k_l1(const float* __restrict__ x, const float* __restrict__ agg1,
                     const float* __restrict__ W1l, const float* __restrict__ b1l,
                     const float* __restrict__ W1r, uchar_t* __restrict__ h8, int rows) {
  int q = blockIdx.x * TPB + threadIdx.x;
  if (q >= rows * 8) return;
  int r = q >> 3, c8 = (q & 7) * 8;
  float a = agg1[r], xx = x[r];
  float vv[8];
#pragma unroll
  for (int k = 0; k < 8; ++k)
    vv[k] = fmaxf(a * W1l[c8 + k] + b1l[c8 + k] + xx * W1r[c8 + k], 0.f);
  unsigned int w0 = __builtin_amdgcn_cvt_pk_fp8_f32(vv[0], vv[1], 0u, false);
  w0 = __builtin_amdgcn_cvt_pk_fp8_f32(vv[2], vv[3], w0, true);
  unsigned int w1 = __builtin_amdgcn_cvt_pk_fp8_f32(vv[4], vv[5], 0u, false);
  w1 = __builtin_amdgcn_cvt_pk_fp8_f32(vv[6], vv[7], w1, true);
  uint2 st; st.x = w0; st.y = w1;
  *(uint2*)(h8 + (size_t)r * 64 + c8) = st;
}

// ---------------- Fused layer: fp8 gather + dual MFMA GEMM + bias + relu ----------
// Block: 256 threads = 4 waves = 32 nodes = 128 GEMM rows. All h in fp8 [N+1][256].
// Epilogue: hOut8 != null -> write fp8 h; else -> fused graph pooling into `pooled`.
#define NB8(ACC, IDX) { \
    uint4 v = *(const uint4*)(h8sl + ((size_t)(unsigned)(IDX) << 8)); \
    auto q0 = __builtin_amdgcn_cvt_pk_f32_fp8(v.x, false); \
    auto q1 = __builtin_amdgcn_cvt_pk_f32_fp8(v.x, true);  \
    auto q2 = __builtin_amdgcn_cvt_pk_f32_fp8(v.y, false); \
    auto q3 = __builtin_amdgcn_cvt_pk_f32_fp8(v.y, true);  \
    auto q4 = __builtin_amdgcn_cvt_pk_f32_fp8(v.z, false); \
    auto q5 = __builtin_amdgcn_cvt_pk_f32_fp8(v.z, true);  \
    auto q6 = __builtin_amdgcn_cvt_pk_f32_fp8(v.w, false); \
    auto q7 = __builtin_amdgcn_cvt_pk_f32_fp8(v.w, true);  \
    ACC[0] += q0[0];  ACC[1] += q0[1];  ACC[2] += q1[0];  ACC[3] += q1[1];  \
    ACC[4] += q2[0];  ACC[5] += q2[1];  ACC[6] += q3[0];  ACC[7] += q3[1];  \
    ACC[8] += q4[0];  ACC[9] += q4[1];  ACC[10] += q5[0]; ACC[11] += q5[1]; \
    ACC[12] += q6[0]; ACC[13] += q6[1]; ACC[14] += q7[0]; ACC[15] += q7[1]; }

__global__ __launch_bounds__(256) void k_layer(
    const uchar_t* __restrict__ hIn8,
    const int* __restrict__ rp, const int* __restrict__ deg, const int* __restrict__ csr,
    const ushort_t* __restrict__ Wlb, const ushort_t* __restrict__ Wrb,
    const float* __restrict__ bias,
    uchar_t* __restrict__ hOut8, float* __restrict__ pooled,
    const int* __restrict__ batch, int N) {
  __shared__ ushort_t As[8192];                 // [128 rows][64 bf16], 16B-unit XOR swizzle
  int t = threadIdx.x;
  int wave = t >> 6, lane = t & 63;
  int g = lane >> 4, l15 = lane & 15;
  int gq = t >> 4, li = t & 15;                 // gather group / lane-in-group
  int n0 = blockIdx.x * 32;
  int r0 = blockIdx.x * 128;

  const uchar_t* h8sl = hIn8 + li * 16;         // lane's 16-feature fp8 slice

  // ---- gather: 16-lane group owns nodes n0+gq*2 .. +1 ----
  for (int k2 = 0; k2 < 2; ++k2) {
    int n = n0 + gq * 2 + k2;
    int b = rp[n], e = rp[n + 1];
    float acc[16];
#pragma unroll
    for (int j = 0; j < 16; ++j) acc[j] = 0.f;
    for (int i = b; i < e; i += 8) {
      int4 c0 = *(const int4*)(csr + i);
      int4 c1 = *(const int4*)(csr + i + 4);
      NB8(acc, c0.x) NB8(acc, c0.y) NB8(acc, c0.z) NB8(acc, c0.w)
      NB8(acc, c1.x) NB8(acc, c1.y) NB8(acc, c1.z) NB8(acc, c1.w)
    }
    int d = deg[n];
    float inv = (d > 0) ? 1.f / (float)d : 0.f;
    ushort8 pk0, pk1;
#pragma unroll
    for (int j = 0; j < 8; ++j) {
      pk0[j] = f2b(acc[j] * inv);
      pk1[j] = f2b(acc[j + 8] * inv);
    }
    int nl = gq * 2 + k2;
    int row = nl * 4 + (li >> 2);
    int cb = (li & 3) * 32;
    int xr = (row & 7) << 4;
    *(ushort8*)((char*)As + row * 128 + (cb ^ xr)) = pk0;
    *(ushort8*)((char*)As + row * 128 + ((cb + 16) ^ xr)) = pk1;
  }
  __syncthreads();

  // ---- fragments: wave owns rows [wave*32, +32) = 2 tiles of 16 ----
  short8v af[2][2], hf[2][2];
#pragma unroll
  for (int tile = 0; tile < 2; ++tile) {
    int arow = wave * 32 + tile * 16 + l15;
    int xr = (arow & 7) << 4;
    af[tile][0] = *(const short8v*)((char*)As + arow * 128 + ((g * 16) ^ xr));
    af[tile][1] = *(const short8v*)((char*)As + arow * 128 + ((g * 16 + 64) ^ xr));
    const uchar_t* hrow8 = hIn8 + (size_t)(r0 + arow) * 64;
    hf[tile][0] = fp8x8_to_bf16(hrow8 + g * 8);
    hf[tile][1] = fp8x8_to_bf16(hrow8 + 32 + g * 8);
  }

  f32x4 fac[4][2];
#pragma unroll
  for (int c = 0; c < 4; ++c) {
    float bv = bias[c * 16 + l15];
    const ushort_t* wl = Wlb + (size_t)(c * 16 + l15) * 64;
    const ushort_t* wr = Wrb + (size_t)(c * 16 + l15) * 64;
    short8v bl0 = *(const short8v*)(wl + g * 8);
    short8v bl1 = *(const short8v*)(wl + 32 + g * 8);
    short8v br0 = *(const short8v*)(wr + g * 8);
    short8v br1 = *(const short8v*)(wr + 32 + g * 8);
#pragma unroll
    for (int tile = 0; tile < 2; ++tile) {
      fac[c][tile] = (f32x4){bv, bv, bv, bv};
      fac[c][tile] = __builtin_amdgcn_mfma_f32_16x16x32_bf16(af[tile][0], bl0, fac[c][tile], 0, 0, 0);
      fac[c][tile] = __builtin_amdgcn_mfma_f32_16x16x32_bf16(af[tile][1], bl1, fac[c][tile], 0, 0, 0);
      fac[c][tile] = __builtin_amdgcn_mfma_f32_16x16x32_bf16(hf[tile][0], br0, fac[c][tile], 0, 0, 0);
      fac[c][tile] = __builtin_amdgcn_mfma_f32_16x16x32_bf16(hf[tile][1], br1, fac[c][tile], 0, 0, 0);
    }
  }

  // ---- epilogue. C/D: col = lane&15, row = (lane>>4)*4 + reg ----
  if (hOut8) {
#pragma unroll
    for (int tile = 0; tile < 2; ++tile)
#pragma unroll
      for (int c = 0; c < 4; ++c)
#pragma unroll
        for (int i2 = 0; i2 < 4; ++i2) {
          int grow = r0 + wave * 32 + tile * 16 + g * 4 + i2;
          float v = fmaxf(fac[c][tile][i2], 0.f);
          hOut8[(size_t)grow * 64 + c * 16 + l15] =
              (uchar_t)(__builtin_amdgcn_cvt_pk_fp8_f32(v, v, 0u, false) & 0xFF);
        }
  } else {
    // fused mean-pool accumulation (sum; k_final divides by gcnt)
    int bF = batch[n0], bL = batch[n0 + 31];
    if (bF == bL) {                           // single-graph block (fast path)
      float* pool_s = (float*)As;             // reuse LDS (4 waves x 256 floats)
      __syncthreads();                        // all As fragment reads complete
      float vv[4][4];
#pragma unroll
      for (int c = 0; c < 4; ++c)
#pragma unroll
        for (int i2 = 0; i2 < 4; ++i2) {
          float v = fmaxf(fac[c][0][i2], 0.f) + fmaxf(fac[c][1][i2], 0.f);
          v += __shfl_xor(v, 16);
          v += __shfl_xor(v, 32);             // summed over g (4 row-groups)
          vv[c][i2] = v;
        }
      if (g == 0) {
#pragma unroll
        for (int c = 0; c < 4; ++c)
#pragma unroll
          for (int i2 = 0; i2 < 4; ++i2)
            pool_s[wave * 256 + i2 * 64 + c * 16 + l15] = vv[c][i2];
      }
      __syncthreads();
      float s = pool_s[t] + pool_s[256 + t] + pool_s[512 + t] + pool_s[768 + t];
      atomicAdd(&pooled[bF * 256 + t], s);
    } else {                                  // graph boundary inside block (rare)
#pragma unroll
      for (int tile = 0; tile < 2; ++tile)
#pragma unroll
        for (int c = 0; c < 4; ++c)
#pragma unroll
          for (int i2 = 0; i2 < 4; ++i2) {
            int grow = r0 + wave * 32 + tile * 16 + g * 4 + i2;
            int nn = grow >> 2;
            atomicAdd(&pooled[batch[nn] * 256 + (grow & 3) * 64 + c * 16 + l15],
                      fmaxf(fac[c][tile][i2], 0.f));
          }
    }
  }
}

__global__ void k_final(const float* __restrict__ pooled, const int* __restrict__ gcnt,
                        const float* __restrict__ Wlin, const float* __restrict__ blin,
                        float* __restrict__ out, int B) {
  int t = blockIdx.x * TPB + threadIdx.x;
  int b = t >> 2, j = t & 3;
  if (b >= B) return;
  float inv = 1.f / fmaxf((float)gcnt[b], 1.f);
  float s = blin[0];
  const float* p = pooled + b * 256 + j * 64;
#pragma unroll
  for (int f = 0; f < 64; ++f) s += p[f] * inv * Wlin[f];
  float z = 1.f / (1.f + expf(-s));
  z += __shfl_xor(z, 1);
  z += __shfl_xor(z, 2);
  if (j == 0) out[b] = 0.25f * z;
}

// ---------------- Host launcher ----------------
extern "C" void kernel_launch(void* const* d_in, const int* in_sizes, int n_in,
                              void* d_out, int out_size, void* d_ws, size_t ws_size,
                              hipStream_t stream) {
  const float* x   = (const float*)d_in[0];
  const int* edge  = (const int*)d_in[1];
  const int* batch = (const int*)d_in[2];
  const float* W1l = (const float*)d_in[3];
  const float* b1l = (const float*)d_in[4];
  const float* W1r = (const float*)d_in[5];
  const float* W2l = (const float*)d_in[6];
  const float* b2l = (const float*)d_in[7];
  const float* W2r = (const float*)d_in[8];
  const float* W3l = (const float*)d_in[9];
  const float* b3l = (const float*)d_in[10];
  const float* W3r = (const float*)d_in[11];
  const float* Wlin = (const float*)d_in[12];
  const float* blin = (const float*)d_in[13];
  float* out = (float*)d_out;

  const int N = in_sizes[0] / 4;          // x: [N,1,4]
  const int E = in_sizes[1] / 2;          // edge_index: [2,E]
  const int B = out_size;
  const int rows = 4 * N;

  const int* srcA = edge;
  const int* dstA = edge + E;

  // workspace carve (~62 MB total)
  char* p = (char*)d_ws;
  auto carve = [&](size_t bytes) -> void* {
    void* r = (void*)p;
    p += (bytes + 255) & ~(size_t)255;
    return r;
  };
  char* zstart = p;
  int* deg     = (int*)carve((size_t)N * 4);         // zeroed region start
  int* gcnt    = (int*)carve((size_t)B * 4);
  float* pooled = (float*)carve((size_t)B * 256 * 4);
  size_t zlen  = (size_t)(p - zstart);               // zeroed region length
  int* rp      = (int*)carve((size_t)(N + 1) * 4);
  int* cursor  = (int*)carve((size_t)N * 4);
  int* bsum    = (int*)carve(4096);
  int* boff    = (int*)carve(4096);
  int* csr     = (int*)carve(((size_t)E + 8 * (size_t)N) * 4);
  float* agg1  = (float*)carve((size_t)N * 4 * 4);
  ushort_t* Wb2l = (ushort_t*)carve(4096 * 2);
  ushort_t* Wb2r = (ushort_t*)carve(4096 * 2);
  ushort_t* Wb3l = (ushort_t*)carve(4096 * 2);
  ushort_t* Wb3r = (ushort_t*)carve(4096 * 2);
  uchar_t* hA8  = (uchar_t*)carve(((size_t)N + 1) * 256);   // fp8 h1 (+zero row N)
  uchar_t* hB8  = (uchar_t*)carve(((size_t)N + 1) * 256);   // fp8 h2 (+zero row N)
  (void)ws_size; (void)n_in;

  hipMemsetAsync(zstart, 0, zlen, stream);           // deg + gcnt + pooled

  int nbScan = (N + TPB - 1) / TPB;

  k_histg<<<(E + TPB - 1) / TPB, TPB, 0, stream>>>(dstA, deg, batch, gcnt, E, N);
  k_cvtw<<<16, TPB, 0, stream>>>(W2l, W2r, W3l, W3r, Wb2l, Wb2r, Wb3l, Wb3r,
                                 hA8 + (size_t)N * 256, hB8 + (size_t)N * 256, 4096);
  k_scan1<<<nbScan, TPB, 0, stream>>>(deg, rp, bsum, N);
  k_scan2<<<1, 1024, 0, stream>>>(bsum, boff, nbScan);
  k_scan3<<<(N + 1 + TPB - 1) / TPB, TPB, 0, stream>>>(rp, boff, bsum, cursor, N, nbScan);
  k_fill<<<(E + TPB - 1) / TPB, TPB, 0, stream>>>(srcA, dstA, cursor, csr, E);

  // layer 1 (F=1): agg (+ csr dummy padding) then MLP -> fp8 h1
  k_agg1<<<(N + TPB - 1) / TPB, TPB, 0, stream>>>((const float4*)x, rp, deg, cursor,
                                                  csr, (float4*)agg1, N);
  k_l1<<<((size_t)rows * 8 + TPB - 1) / TPB, TPB, 0, stream>>>(x, agg1, W1l, b1l, W1r, hA8, rows);

  // layers 2 & 3: fused fp8 gather + dual MFMA GEMM (+ fused pooling in layer 3)
  int nbLayer = (N + 31) / 32;
  k_layer<<<nbLayer, TPB, 0, stream>>>(hA8, rp, deg, csr, Wb2l, Wb2r, b2l,
                                       hB8, (float*)nullptr, batch, N);
  k_layer<<<nbLayer, TPB, 0, stream>>>(hB8, rp, deg, csr, Wb3l, Wb3r, b3l,
                                       (uchar_t*)nullptr, pooled, batch, N);

  // head
  k_final<<<(B * 4 + TPB - 1) / TPB, TPB, 0, stream>>>(pooled, gcnt, Wlin, blin, out, B);
}

// Round 9
// 359.400 us; speedup vs baseline: 1.3258x; 1.0108x over previous
//
#include <hip/hip_runtime.h>
#include <math.h>

#define TPB 256

typedef unsigned short ushort_t;
typedef unsigned char uchar_t;
typedef __attribute__((ext_vector_type(8))) short short8v;     // 8 bf16 (4 VGPRs), MFMA A/B frag
typedef __attribute__((ext_vector_type(4))) float f32x4;       // MFMA C/D frag
typedef __attribute__((ext_vector_type(8))) unsigned short ushort8;

__device__ __forceinline__ unsigned short f2b(float f) {
  union { float f; unsigned int i; } c; c.f = f;
  unsigned int x = c.i;
  x += 0x7FFFu + ((x >> 16) & 1u);           // round-to-nearest-even
  return (unsigned short)(x >> 16);
}
__device__ __forceinline__ float b2f(unsigned short u) {
  union { unsigned int i; float f; } c; c.i = ((unsigned int)u) << 16; return c.f;
}

// fp8 row (8 bytes) -> bf16 MFMA half-fragment (exact: e4m3 subset of bf16)
__device__ __forceinline__ short8v fp8x8_to_bf16(const uchar_t* p) {
  uint2 u = *(const uint2*)p;
  auto p0 = __builtin_amdgcn_cvt_pk_f32_fp8(u.x, false);
  auto p1 = __builtin_amdgcn_cvt_pk_f32_fp8(u.x, true);
  auto p2 = __builtin_amdgcn_cvt_pk_f32_fp8(u.y, false);
  auto p3 = __builtin_amdgcn_cvt_pk_f32_fp8(u.y, true);
  ushort8 o;
  o[0] = f2b(p0[0]); o[1] = f2b(p0[1]); o[2] = f2b(p1[0]); o[3] = f2b(p1[1]);
  o[4] = f2b(p2[0]); o[5] = f2b(p2[1]); o[6] = f2b(p3[0]); o[7] = f2b(p3[1]);
  union { ushort8 a; short8v b; } c; c.a = o; return c.b;
}

// ---------------- hist (in-degree) + per-graph node counts ----------------
__global__ void k_histg(const int* __restrict__ dst, int* deg,
                        const int* __restrict__ batch, int* gcnt, int E, int N) {
  int t = blockIdx.x * TPB + threadIdx.x;
  if (t < E) atomicAdd(&deg[dst[t]], 1);
  int n0 = t * 16;
  if (n0 < N) {
    int n1 = min(n0 + 16, N);
    int cur = batch[n0];
    int c = 0;
    for (int n = n0; n < n1; ++n) {
      int b = batch[n];
      if (b != cur) { atomicAdd(&gcnt[cur], c); cur = b; c = 0; }
      ++c;
    }
    atomicAdd(&gcnt[cur], c);
  }
}

// scan input = deg rounded up to multiple of 8
__global__ void k_scan1(const int* __restrict__ deg, int* rp, int* bsum, int N) {
  __shared__ int s[TPB];
  int t = threadIdx.x;
  int i = blockIdx.x * TPB + t;
  int v = (i < N) ? ((deg[i] + 7) & ~7) : 0;
  s[t] = v;
  __syncthreads();
  for (int d = 1; d < TPB; d <<= 1) {
    int u = (t >= d) ? s[t - d] : 0;
    __syncthreads();
    s[t] += u;
    __syncthreads();
  }
  if (i < N) rp[i] = s[t] - v;
  if (t == TPB - 1) bsum[blockIdx.x] = s[t];
}

__global__ void k_scan2(const int* bsum, int* boff, int nb) {
  __shared__ int s[1024];
  int t = threadIdx.x;
  int v = (t < nb) ? bsum[t] : 0;
  s[t] = v;
  __syncthreads();
  for (int d = 1; d < 1024; d <<= 1) {
    int u = (t >= d) ? s[t - d] : 0;
    __syncthreads();
    s[t] += u;
    __syncthreads();
  }
  if (t < nb) boff[t] = s[t] - v;
}

__global__ void k_scan3(int* rp, const int* __restrict__ boff, const int* __restrict__ bsum,
                        int* cursor, int N, int nb) {
  int i = blockIdx.x * TPB + threadIdx.x;
  if (i < N) {
    int v = rp[i] + boff[i >> 8];
    rp[i] = v;
    cursor[i] = v;
  } else if (i == N) {
    rp[N] = boff[nb - 1] + bsum[nb - 1];       // total padded edges
  }
}

__global__ void k_fill(const int* __restrict__ src, const int* __restrict__ dst,
                       int* cursor, int* __restrict__ csr, int E) {
  int e = blockIdx.x * TPB + threadIdx.x;
  if (e < E) {
    int p = atomicAdd(&cursor[dst[e]], 1);
    csr[p] = src[e];
  }
}

// ---------------- weight fp32 -> bf16 (+ zero-row init for dummy edges) --------
__global__ void k_cvtw(const float* __restrict__ s0, const float* __restrict__ s1,
                       const float* __restrict__ s2, const float* __restrict__ s3,
                       ushort_t* d0, ushort_t* d1, ushort_t* d2, ushort_t* d3,
                       uchar_t* zr0, uchar_t* zr1, int n) {
  int i = blockIdx.x * TPB + threadIdx.x;
  if (i < n) { d0[i] = f2b(s0[i]); d1[i] = f2b(s1[i]); d2[i] = f2b(s2[i]); d3[i] = f2b(s3[i]); }
  if (blockIdx.x == 0) {
    if (threadIdx.x < 64) ((int*)zr0)[threadIdx.x] = 0;
    else if (threadIdx.x < 128) ((int*)zr1)[threadIdx.x - 64] = 0;
  }
}

// ---------------- Layer 1 agg (F=1) + CSR dummy padding ----------------
__global__ void k_agg1(const float4* __restrict__ x, const int* __restrict__ rp,
                       const int* __restrict__ deg, const int* __restrict__ cursor,
                       int* __restrict__ csr, float4* __restrict__ agg1, int N) {
  int n = blockIdx.x * TPB + threadIdx.x;
  if (n >= N) return;
  int b = rp[n], e = rp[n + 1];
  float4 a = make_float4(0.f, 0.f, 0.f, 0.f);
  for (int i = b; i < e; i += 8) {
    int4 c0 = *(const int4*)(csr + i);
    int4 c1 = *(const int4*)(csr + i + 4);
    int id[8] = {c0.x, c0.y, c0.z, c0.w, c1.x, c1.y, c1.z, c1.w};
#pragma unroll
    for (int j = 0; j < 8; ++j) {
      unsigned idx = min((unsigned)id[j], (unsigned)(N - 1));  // clamp garbage/dummy
      float m = ((unsigned)id[j] < (unsigned)N) ? 1.f : 0.f;
      float4 v = x[idx];
      a.x += v.x * m; a.y += v.y * m; a.z += v.z * m; a.w += v.w * m;
    }
  }
  int d = deg[n];
  float inv = (d > 0) ? 1.f / (float)d : 0.f;
  a.x *= inv; a.y *= inv; a.z *= inv; a.w *= inv;
  agg1[n] = a;
  // pad this node's dummy CSR slots with N (zero row) for k_layer
  int c = cursor[n];
  for (int p2 = c; p2 < e; ++p2) csr[p2] = N;
}

// h1 row r (fp8 only): relu(agg1[r]*W1l[c] + b1l[c] + x[r]*W1r[c])
__global__ void k_l1(const float* __restrict__ x, const float* __restrict__ agg1,
                     const float* __restrict__ W1l, const float* __restrict__ b1l,
                     const float* __restrict__ W1r, uchar_t* __restrict__ h8, int rows) {
  int q = blockIdx.x * TPB + threadIdx.x;
  if (q >= rows * 8) return;
  int r = q >> 3, c8 = (q & 7) * 8;
  float a = agg1[r], xx = x[r];
  float vv[8];
#pragma unroll
  for (int k = 0; k < 8; ++k)
    vv[k] = fmaxf(a * W1l[c8 + k] + b1l[c8 + k] + xx * W1r[c8 + k], 0.f);
  unsigned int w0 = __builtin_amdgcn_cvt_pk_fp8_f32(vv[0], vv[1], 0u, false);
  w0 = __builtin_amdgcn_cvt_pk_fp8_f32(vv[2], vv[3], w0, true);
  unsigned int w1 = __builtin_amdgcn_cvt_pk_fp8_f32(vv[4], vv[5], 0u, false);
  w1 = __builtin_amdgcn_cvt_pk_fp8_f32(vv[6], vv[7], w1, true);
  uint2 st; st.x = w0; st.y = w1;
  *(uint2*)(h8 + (size_t)r * 64 + c8) = st;
}

// ---------------- Fused layer: fp8 gather + dual MFMA GEMM + bias + relu ----------
// Block: 256 threads = 4 waves = 32 nodes = 128 GEMM rows. All h in fp8 [N+1][256].
// Epilogue: hOut8 != null -> write fp8 h; else -> fused graph pooling into `pooled`.
#define NB8(ACC, IDX) { \
    uint4 v = *(const uint4*)(h8sl + ((size_t)(unsigned)(IDX) << 8)); \
    auto q0 = __builtin_amdgcn_cvt_pk_f32_fp8(v.x, false); \
    auto q1 = __builtin_amdgcn_cvt_pk_f32_fp8(v.x, true);  \
    auto q2 = __builtin_amdgcn_cvt_pk_f32_fp8(v.y, false); \
    auto q3 = __builtin_amdgcn_cvt_pk_f32_fp8(v.y, true);  \
    auto q4 = __builtin_amdgcn_cvt_pk_f32_fp8(v.z, false); \
    auto q5 = __builtin_amdgcn_cvt_pk_f32_fp8(v.z, true);  \
    auto q6 = __builtin_amdgcn_cvt_pk_f32_fp8(v.w, false); \
    auto q7 = __builtin_amdgcn_cvt_pk_f32_fp8(v.w, true);  \
    ACC[0] += q0[0];  ACC[1] += q0[1];  ACC[2] += q1[0];  ACC[3] += q1[1];  \
    ACC[4] += q2[0];  ACC[5] += q2[1];  ACC[6] += q3[0];  ACC[7] += q3[1];  \
    ACC[8] += q4[0];  ACC[9] += q4[1];  ACC[10] += q5[0]; ACC[11] += q5[1]; \
    ACC[12] += q6[0]; ACC[13] += q6[1]; ACC[14] += q7[0]; ACC[15] += q7[1]; }

__global__ __launch_bounds__(256) void k_layer(
    const uchar_t* __restrict__ hIn8,
    const int* __restrict__ rp, const int* __restrict__ deg, const int* __restrict__ csr,
    const ushort_t* __restrict__ Wlb, const ushort_t* __restrict__ Wrb,
    const float* __restrict__ bias,
    uchar_t* __restrict__ hOut8, float* __restrict__ pooled,
    const int* __restrict__ batch, int N) {
  __shared__ ushort_t As[8192];                 // [128 rows][64 bf16], 16B-unit XOR swizzle
  int t = threadIdx.x;
  int wave = t >> 6, lane = t & 63;
  int g = lane >> 4, l15 = lane & 15;
  int gq = t >> 4, li = t & 15;                 // gather group / lane-in-group
  int n0 = blockIdx.x * 32;
  int r0 = blockIdx.x * 128;

  const uchar_t* h8sl = hIn8 + li * 16;         // lane's 16-feature fp8 slice

  // ---- gather: 16-lane group owns nodes n0+gq*2 .. +1 ----
  for (int k2 = 0; k2 < 2; ++k2) {
    int n = n0 + gq * 2 + k2;
    int b = rp[n], e = rp[n + 1];
    float acc[16];
#pragma unroll
    for (int j = 0; j < 16; ++j) acc[j] = 0.f;
    for (int i = b; i < e; i += 8) {
      int4 c0 = *(const int4*)(csr + i);
      int4 c1 = *(const int4*)(csr + i + 4);
      NB8(acc, c0.x) NB8(acc, c0.y) NB8(acc, c0.z) NB8(acc, c0.w)
      NB8(acc, c1.x) NB8(acc, c1.y) NB8(acc, c1.z) NB8(acc, c1.w)
    }
    int d = deg[n];
    float inv = (d > 0) ? 1.f / (float)d : 0.f;
    ushort8 pk0, pk1;
#pragma unroll
    for (int j = 0; j < 8; ++j) {
      pk0[j] = f2b(acc[j] * inv);
      pk1[j] = f2b(acc[j + 8] * inv);
    }
    int nl = gq * 2 + k2;
    int row = nl * 4 + (li >> 2);
    int cb = (li & 3) * 32;
    int xr = (row & 7) << 4;
    *(ushort8*)((char*)As + row * 128 + (cb ^ xr)) = pk0;
    *(ushort8*)((char*)As + row * 128 + ((cb + 16) ^ xr)) = pk1;
  }
  __syncthreads();

  // ---- fragments: wave owns rows [wave*32, +32) = 2 tiles of 16 ----
  short8v af[2][2], hf[2][2];
#pragma unroll
  for (int tile = 0; tile < 2; ++tile) {
    int arow = wave * 32 + tile * 16 + l15;
    int xr = (arow & 7) << 4;
    af[tile][0] = *(const short8v*)((char*)As + arow * 128 + ((g * 16) ^ xr));
    af[tile][1] = *(const short8v*)((char*)As + arow * 128 + ((g * 16 + 64) ^ xr));
    const uchar_t* hrow8 = hIn8 + (size_t)(r0 + arow) * 64;
    hf[tile][0] = fp8x8_to_bf16(hrow8 + g * 8);
    hf[tile][1] = fp8x8_to_bf16(hrow8 + 32 + g * 8);
  }

  f32x4 fac[4][2];
#pragma unroll
  for (int c = 0; c < 4; ++c) {
    float bv = bias[c * 16 + l15];
    const ushort_t* wl = Wlb + (size_t)(c * 16 + l15) * 64;
    const ushort_t* wr = Wrb + (size_t)(c * 16 + l15) * 64;
    short8v bl0 = *(const short8v*)(wl + g * 8);
    short8v bl1 = *(const short8v*)(wl + 32 + g * 8);
    short8v br0 = *(const short8v*)(wr + g * 8);
    short8v br1 = *(const short8v*)(wr + 32 + g * 8);
#pragma unroll
    for (int tile = 0; tile < 2; ++tile) {
      fac[c][tile] = (f32x4){bv, bv, bv, bv};
      fac[c][tile] = __builtin_amdgcn_mfma_f32_16x16x32_bf16(af[tile][0], bl0, fac[c][tile], 0, 0, 0);
      fac[c][tile] = __builtin_amdgcn_mfma_f32_16x16x32_bf16(af[tile][1], bl1, fac[c][tile], 0, 0, 0);
      fac[c][tile] = __builtin_amdgcn_mfma_f32_16x16x32_bf16(hf[tile][0], br0, fac[c][tile], 0, 0, 0);
      fac[c][tile] = __builtin_amdgcn_mfma_f32_16x16x32_bf16(hf[tile][1], br1, fac[c][tile], 0, 0, 0);
    }
  }

  // ---- epilogue. C/D: col = lane&15, row = (lane>>4)*4 + reg ----
  if (hOut8) {
#pragma unroll
    for (int tile = 0; tile < 2; ++tile)
#pragma unroll
      for (int c = 0; c < 4; ++c)
#pragma unroll
        for (int i2 = 0; i2 < 4; ++i2) {
          int grow = r0 + wave * 32 + tile * 16 + g * 4 + i2;
          float v = fmaxf(fac[c][tile][i2], 0.f);
          hOut8[(size_t)grow * 64 + c * 16 + l15] =
              (uchar_t)(__builtin_amdgcn_cvt_pk_fp8_f32(v, v, 0u, false) & 0xFF);
        }
  } else {
    // fused mean-pool accumulation (sum; k_final divides by gcnt)
    int bF = batch[n0], bL = batch[n0 + 31];
    if (bF == bL) {                           // single-graph block (fast path)
      float* pool_s = (float*)As;             // reuse LDS (4 waves x 256 floats)
      __syncthreads();                        // all As fragment reads complete
      float vv[4][4];
#pragma unroll
      for (int c = 0; c < 4; ++c)
#pragma unroll
        for (int i2 = 0; i2 < 4; ++i2) {
          float v = fmaxf(fac[c][0][i2], 0.f) + fmaxf(fac[c][1][i2], 0.f);
          v += __shfl_xor(v, 16);
          v += __shfl_xor(v, 32);             // summed over g (4 row-groups)
          vv[c][i2] = v;
        }
      if (g == 0) {
#pragma unroll
        for (int c = 0; c < 4; ++c)
#pragma unroll
          for (int i2 = 0; i2 < 4; ++i2)
            pool_s[wave * 256 + i2 * 64 + c * 16 + l15] = vv[c][i2];
      }
      __syncthreads();
      float s = pool_s[t] + pool_s[256 + t] + pool_s[512 + t] + pool_s[768 + t];
      atomicAdd(&pooled[bF * 256 + t], s);
    } else {                                  // graph boundary inside block (rare)
#pragma unroll
      for (int tile = 0; tile < 2; ++tile)
#pragma unroll
        for (int c = 0; c < 4; ++c)
#pragma unroll
          for (int i2 = 0; i2 < 4; ++i2) {
            int grow = r0 + wave * 32 + tile * 16 + g * 4 + i2;
            int nn = grow >> 2;
            atomicAdd(&pooled[batch[nn] * 256 + (grow & 3) * 64 + c * 16 + l15],
                      fmaxf(fac[c][tile][i2], 0.f));
          }
    }
  }
}

__global__ void k_final(const float* __restrict__ pooled, const int* __restrict__ gcnt,
                        const float* __restrict__ Wlin, const float* __restrict__ blin,
                        float* __restrict__ out, int B) {
  int t = blockIdx.x * TPB + threadIdx.x;
  int b = t >> 2, j = t & 3;
  if (b >= B) return;
  float inv = 1.f / fmaxf((float)gcnt[b], 1.f);
  float s = blin[0];
  const float* p = pooled + b * 256 + j * 64;
#pragma unroll
  for (int f = 0; f < 64; ++f) s += p[f] * inv * Wlin[f];
  float z = 1.f / (1.f + expf(-s));
  z += __shfl_xor(z, 1);
  z += __shfl_xor(z, 2);
  if (j == 0) out[b] = 0.25f * z;
}

// ---------------- Host launcher ----------------
extern "C" void kernel_launch(void* const* d_in, const int* in_sizes, int n_in,
                              void* d_out, int out_size, void* d_ws, size_t ws_size,
                              hipStream_t stream) {
  const float* x   = (const float*)d_in[0];
  const int* edge  = (const int*)d_in[1];
  const int* batch = (const int*)d_in[2];
  const float* W1l = (const float*)d_in[3];
  const float* b1l = (const float*)d_in[4];
  const float* W1r = (const float*)d_in[5];
  const float* W2l = (const float*)d_in[6];
  const float* b2l = (const float*)d_in[7];
  const float* W2r = (const float*)d_in[8];
  const float* W3l = (const float*)d_in[9];
  const float* b3l = (const float*)d_in[10];
  const float* W3r = (const float*)d_in[11];
  const float* Wlin = (const float*)d_in[12];
  const float* blin = (const float*)d_in[13];
  float* out = (float*)d_out;

  const int N = in_sizes[0] / 4;          // x: [N,1,4]
  const int E = in_sizes[1] / 2;          // edge_index: [2,E]
  const int B = out_size;
  const int rows = 4 * N;

  const int* srcA = edge;
  const int* dstA = edge + E;

  // workspace carve (~62 MB total)
  char* p = (char*)d_ws;
  auto carve = [&](size_t bytes) -> void* {
    void* r = (void*)p;
    p += (bytes + 255) & ~(size_t)255;
    return r;
  };
  char* zstart = p;
  int* deg     = (int*)carve((size_t)N * 4);         // zeroed region start
  int* gcnt    = (int*)carve((size_t)B * 4);
  float* pooled = (float*)carve((size_t)B * 256 * 4);
  size_t zlen  = (size_t)(p - zstart);               // zeroed region length
  int* rp      = (int*)carve((size_t)(N + 1) * 4);
  int* cursor  = (int*)carve((size_t)N * 4);
  int* bsum    = (int*)carve(4096);
  int* boff    = (int*)carve(4096);
  int* csr     = (int*)carve(((size_t)E + 8 * (size_t)N) * 4);
  float* agg1  = (float*)carve((size_t)N * 4 * 4);
  ushort_t* Wb2l = (ushort_t*)carve(4096 * 2);
  ushort_t* Wb2r = (ushort_t*)carve(4096 * 2);
  ushort_t* Wb3l = (ushort_t*)carve(4096 * 2);
  ushort_t* Wb3r = (ushort_t*)carve(4096 * 2);
  uchar_t* hA8  = (uchar_t*)carve(((size_t)N + 1) * 256);   // fp8 h1 (+zero row N)
  uchar_t* hB8  = (uchar_t*)carve(((size_t)N + 1) * 256);   // fp8 h2 (+zero row N)
  (void)ws_size; (void)n_in;

  hipMemsetAsync(zstart, 0, zlen, stream);           // deg + gcnt + pooled

  int nbScan = (N + TPB - 1) / TPB;

  k_histg<<<(E + TPB - 1) / TPB, TPB, 0, stream>>>(dstA, deg, batch, gcnt, E, N);
  k_cvtw<<<16, TPB, 0, stream>>>(W2l, W2r, W3l, W3r, Wb2l, Wb2r, Wb3l, Wb3r,
                                 hA8 + (size_t)N * 256, hB8 + (size_t)N * 256, 4096);
  k_scan1<<<nbScan, TPB, 0, stream>>>(deg, rp, bsum, N);
  k_scan2<<<1, 1024, 0, stream>>>(bsum, boff, nbScan);
  k_scan3<<<(N + 1 + TPB - 1) / TPB, TPB, 0, stream>>>(rp, boff, bsum, cursor, N, nbScan);
  k_fill<<<(E + TPB - 1) / TPB, TPB, 0, stream>>>(srcA, dstA, cursor, csr, E);

  // layer 1 (F=1): agg (+ csr dummy padding) then MLP -> fp8 h1
  k_agg1<<<(N + TPB - 1) / TPB, TPB, 0, stream>>>((const float4*)x, rp, deg, cursor,
                                                  csr, (float4*)agg1, N);
  k_l1<<<((size_t)rows * 8 + TPB - 1) / TPB, TPB, 0, stream>>>(x, agg1, W1l, b1l, W1r, hA8, rows);

  // layers 2 & 3: fused fp8 gather + dual MFMA GEMM (+ fused pooling in layer 3)
  int nbLayer = (N + 31) / 32;
  k_layer<<<nbLayer, TPB, 0, stream>>>(hA8, rp, deg, csr, Wb2l, Wb2r, b2l,
                                       hB8, (float*)nullptr, batch, N);
  k_layer<<<nbLayer, TPB, 0, stream>>>(hB8, rp, deg, csr, Wb3l, Wb3r, b3l,
                                       (uchar_t*)nullptr, pooled, batch, N);

  // head
  k_final<<<(B * 4 + TPB - 1) / TPB, TPB, 0, stream>>>(pooled, gcnt, Wlin, blin, out, B);
}